// Round 4
// baseline (719.627 us; speedup 1.0000x reference)
//
#include <hip/hip_runtime.h>
#include <hip/hip_bf16.h>
#include <cstdint>
#include <cstddef>

// Problem constants (match reference)
#define N_NODES  20000
#define N_EDGES  320000
#define E_TOTAL  (N_EDGES + N_NODES)   // with self loops = 340000
#define N_GRAPHS 256
#define F_NODE   11
#define F_TDA    30
#define DIM      128
#define NHEAD    4
#define NLAYER   3
#define NTASK    6
#define NEG_SLOPE 0.2f
#define LN_EPS   1e-5f
#define CSR_CAP  64   // fixed per-node capacity; deg ~ Poisson(17), P(>64) ~ 0

typedef short bf16x8 __attribute__((ext_vector_type(8)));
typedef float f32x4  __attribute__((ext_vector_type(4)));
typedef float f32x2  __attribute__((ext_vector_type(2)));

__device__ inline unsigned short f2b(float f) {
    unsigned int u = __builtin_bit_cast(unsigned int, f);
    u += 0x7fffu + ((u >> 16) & 1u);
    return (unsigned short)(u >> 16);
}
__device__ inline float blo(unsigned int u) { return __builtin_bit_cast(float, u << 16); }
__device__ inline float bhi(unsigned int u) { return __builtin_bit_cast(float, u & 0xffff0000u); }
__device__ inline float b2f(unsigned short b) {
    return __builtin_bit_cast(float, ((unsigned int)b) << 16);
}

// ---------------------------------------------------------------------------
// qprep: [0,768) Wstack cast (k-permuted, 0.25 folded); [768,1152) q vectors;
// [1152,1172) zero degs. Runs BEFORE prep so prep can read q_s/q_d safely.
// ---------------------------------------------------------------------------
__global__ __launch_bounds__(256) void qprep_kernel(const float* __restrict__ w_gat,
                                                    const float* __restrict__ a_src,
                                                    const float* __restrict__ a_dst,
                                                    unsigned short* __restrict__ wt2,
                                                    float* __restrict__ q_s,
                                                    float* __restrict__ q_d,
                                                    int* __restrict__ degs) {
    int bx = blockIdx.x;
    int tid = threadIdx.x;
    if (bx < 768) {
        int i = bx * 256 + tid;              // over 3*128*512
        if (i >= NLAYER * 128 * 512) return;
        int l = i >> 16;
        int rem = i & 65535;
        int jcol = rem >> 9;
        int p = rem & 511;
        int lanep = p >> 3, j8 = p & 7;
        int hp = j8 >> 1, bb = j8 & 1;
        int d = lanep * 2 + bb;
        wt2[i] = f2b(w_gat[(size_t)l * 65536 + (size_t)d * 512 + hp * 128 + jcol] * 0.25f);
    } else if (bx < 1152) {
        int bx2 = bx - 768;                  // over 3*128
        int l = bx2 >> 7, k = bx2 & 127;
        int hh_ = tid >> 6, lane = tid & 63;
        int d0 = lane * 2;
        size_t wb = (size_t)l * 65536 + (size_t)k * 512 + hh_ * 128;
        size_t ab = (size_t)l * 512 + hh_ * 128;
        float ps = w_gat[wb + d0] * a_src[ab + d0] + w_gat[wb + d0 + 1] * a_src[ab + d0 + 1];
        float pd = w_gat[wb + d0] * a_dst[ab + d0] + w_gat[wb + d0 + 1] * a_dst[ab + d0 + 1];
#pragma unroll
        for (int off = 32; off; off >>= 1) { ps += __shfl_xor(ps, off); pd += __shfl_xor(pd, off); }
        if (lane == 0) {
            q_s[(size_t)(l * 128 + k) * 4 + hh_] = ps;
            q_d[(size_t)(l * 128 + k) * 4 + hh_] = pd;
        }
    } else {
        int i0 = (bx - 1152) * 1024 + tid;
#pragma unroll
        for (int r = 0; r < 4; r++) {
            int i = i0 + r * 256;
            if (i < N_NODES) degs[i] = 0;
        }
    }
}

// ---------------------------------------------------------------------------
// prep: [0,2500) fat projection (8 nodes/block) + layer-0 alpha;
//       [2500, +333) fixed-capacity CSR scatter, 4 edges/thread.
// ---------------------------------------------------------------------------
__global__ __launch_bounds__(256) void prep_kernel(const float* __restrict__ x,
                                                   const float* __restrict__ w,
                                                   const float* __restrict__ b,
                                                   unsigned short* __restrict__ h_bf,
                                                   const float* __restrict__ q_s,
                                                   const float* __restrict__ q_d,
                                                   float4* __restrict__ als4,
                                                   float4* __restrict__ ald4,
                                                   const int* __restrict__ edge_index,
                                                   int* __restrict__ degs,
                                                   int* __restrict__ csr_src) {
    int bx = blockIdx.x;
    int tid = threadIdx.x;
    if (bx < 2500) {
        __shared__ float xr[8][F_NODE];
        __shared__ float vbuf[8][128];
        __shared__ float qs_t[512];
        __shared__ float qd_t[512];
        qs_t[tid] = q_s[tid]; qs_t[256 + tid] = q_s[256 + tid];
        qd_t[tid] = q_d[tid]; qd_t[256 + tid] = q_d[256 + tid];
        if (tid < 8 * F_NODE) {
            int nl = tid / F_NODE, k = tid % F_NODE;
            xr[nl][k] = x[(size_t)(bx * 8 + nl) * F_NODE + k];
        }
        __syncthreads();
        int d = tid & 127;
        int halfsel = tid >> 7;
#pragma unroll
        for (int p = 0; p < 4; p++) {
            int nl = p * 2 + halfsel;
            float acc = b[d];
#pragma unroll
            for (int k = 0; k < F_NODE; k++) acc += xr[nl][k] * w[k * DIM + d];
            float v = fmaxf(acc, 0.f);
            h_bf[(size_t)(bx * 8 + nl) * DIM + d] = f2b(v);
            vbuf[nl][d] = v;
        }
        __syncthreads();
        int wave = tid >> 6, lane = tid & 63;
#pragma unroll
        for (int t = 0; t < 2; t++) {
            int nl = wave * 2 + t;
            int n = bx * 8 + nl;
            float2 v2 = *(const float2*)&vbuf[nl][2 * lane];
            int k4 = 2 * lane * 4;
            float ps[4], pd[4];
#pragma unroll
            for (int hh_ = 0; hh_ < 4; hh_++) {
                ps[hh_] = v2.x * qs_t[k4 + hh_] + v2.y * qs_t[k4 + 4 + hh_];
                pd[hh_] = v2.x * qd_t[k4 + hh_] + v2.y * qd_t[k4 + 4 + hh_];
            }
#pragma unroll
            for (int off = 32; off; off >>= 1) {
#pragma unroll
                for (int hh_ = 0; hh_ < 4; hh_++) {
                    ps[hh_] += __shfl_xor(ps[hh_], off);
                    pd[hh_] += __shfl_xor(pd[hh_], off);
                }
            }
            if (lane == 0) {
                als4[n] = make_float4(ps[0], ps[1], ps[2], ps[3]);
                ald4[n] = make_float4(pd[0], pd[1], pd[2], pd[3]);
            }
        }
    } else {
        int base = (bx - 2500) * 1024;
#pragma unroll
        for (int k = 0; k < 4; k++) {
            int e = base + k * 256 + tid;
            if (e < E_TOTAL) {
                int s, d;
                if (e < N_EDGES) { s = edge_index[e]; d = edge_index[N_EDGES + e]; }
                else             { s = e - N_EDGES;   d = s; }
                int pos = atomicAdd(&degs[d], 1);
                if (pos < CSR_CAP) csr_src[d * CSR_CAP + pos] = s;
            }
        }
    }
}

// ---------------------------------------------------------------------------
// h-space aggregation (R15/R17-proven structure). Wave per node; lane owns
// feature pair (2*lane, 2*lane+1) for all 4 heads.
// REPS>1: diagnostic replay (bit-idempotent — reads {h_bf,als4,ald4,degs,
// csr_src}, writes only z deterministically) to surface this dispatch above
// the 44us harness fills in rocprof top-5. Interpret dur/REPS as per-rep time.
// ---------------------------------------------------------------------------
template<int LYR, int REPS>
__global__ __launch_bounds__(256) void agg2_kernel(const unsigned short* __restrict__ h_bf,
                                                   const float4* __restrict__ als4,
                                                   const float4* __restrict__ ald4,
                                                   const int* __restrict__ degs,
                                                   const int* __restrict__ csr_src,
                                                   unsigned short* __restrict__ z) {
    int wave = threadIdx.x >> 6, lane = threadIdx.x & 63;
    int n = blockIdx.x * 4 + wave;
    if (n >= N_NODES) return;

    int deg = degs[n];
    const int* __restrict__ srcp = csr_src + (size_t)n * CSR_CAP;
    const unsigned int* __restrict__ h32 = (const unsigned int*)h_bf;
    const float* __restrict__ als_f = (const float*)als4;
    float4 ad = ald4[n];

    int l4 = lane & 3;                   // head this lane's w-computation covers
    int le = (lane >> 2) & 3;            // edge-in-batch this lane covers
    float adh = (l4 == 0) ? ad.x : ((l4 == 1) ? ad.y : ((l4 == 2) ? ad.z : ad.w));

#pragma unroll 1
    for (int rep = 0; rep < REPS; ++rep) {
        f32x2 acc2[4] = {};
        float lsOwn = 0.f;

        int s0 = 0, s1 = 0, s2 = 0, s3 = 0;
        if (deg >= 4) { s0 = srcp[0]; s1 = srcp[1]; s2 = srcp[2]; s3 = srcp[3]; }
        int e = 0;
        for (; e + 4 <= deg; ) {
            int c0 = s0, c1 = s1, c2 = s2, c3 = s3;
            unsigned int hv0 = h32[(size_t)c0 * 64 + lane];
            unsigned int hv1 = h32[(size_t)c1 * 64 + lane];
            unsigned int hv2 = h32[(size_t)c2 * 64 + lane];
            unsigned int hv3 = h32[(size_t)c3 * 64 + lane];
            int se = (le == 0) ? c0 : ((le == 1) ? c1 : ((le == 2) ? c2 : c3));
            float a = als_f[(size_t)se * 4 + l4];
            int en = e + 4;
            if (en + 4 <= deg) { s0 = srcp[en]; s1 = srcp[en + 1]; s2 = srcp[en + 2]; s3 = srcp[en + 3]; }
            float v = a + adh;
            v = fmaxf(v, NEG_SLOPE * v);
            float w = __expf(fminf(v, 60.f));
            lsOwn += w;
            float wv[16];
#pragma unroll
            for (int j = 0; j < 16; j++) wv[j] = __shfl(w, j);
            unsigned int hv[4] = { hv0, hv1, hv2, hv3 };
#pragma unroll
            for (int j = 0; j < 4; j++) {
                f32x2 f; f.x = blo(hv[j]); f.y = bhi(hv[j]);
                acc2[0] += wv[j * 4 + 0] * f;
                acc2[1] += wv[j * 4 + 1] * f;
                acc2[2] += wv[j * 4 + 2] * f;
                acc2[3] += wv[j * 4 + 3] * f;
            }
            e = en;
        }
        float ls[4];
#pragma unroll
        for (int hh_ = 0; hh_ < 4; hh_++) {
            ls[hh_] = __shfl(lsOwn, hh_) + __shfl(lsOwn, 4 + hh_)
                    + __shfl(lsOwn, 8 + hh_) + __shfl(lsOwn, 12 + hh_);
        }
        for (; e < deg; e++) {
            int s = srcp[e];
            float4 a4 = als4[s];
            unsigned int vv = h32[(size_t)s * 64 + lane];
            f32x2 f; f.x = blo(vv); f.y = bhi(vv);
#pragma unroll
            for (int hh_ = 0; hh_ < 4; hh_++) {
                float v = (&a4.x)[hh_] + (&ad.x)[hh_];
                v = (v > 0.f) ? v : NEG_SLOPE * v;
                float w = __expf(fminf(v, 60.f));
                ls[hh_] += w;
                acc2[hh_] += w * f;
            }
        }
        uint4 pb;
        unsigned int* pc = &pb.x;
#pragma unroll
        for (int hh_ = 0; hh_ < 4; hh_++) {
            float il = 1.f / ls[hh_];
            pc[hh_] = (unsigned)f2b(acc2[hh_].x * il) | ((unsigned)f2b(acc2[hh_].y * il) << 16);
        }
        *(uint4*)(z + (size_t)n * 512 + lane * 8) = pb;
    }
}

// ---------------------------------------------------------------------------
// zgemm (templated per layer): out = z[M,512] @ wt2[128,512]^T, fused bias +
// LN + ReLU + bf16 residual + next-layer alpha. 64x128 tile, K in 4 chunks.
// REPS>1: diagnostic replay (idempotent for LYR=2: no alpha writes).
// ---------------------------------------------------------------------------
template<int LYR, int REPS>
__global__ __launch_bounds__(256) void zgemm_kernel(const unsigned short* __restrict__ z,
                                                    const unsigned short* __restrict__ wt2_l,
                                                    const float* __restrict__ b_gat,
                                                    const float* __restrict__ ln_w,
                                                    const float* __restrict__ ln_b,
                                                    const unsigned short* __restrict__ hb_in,
                                                    unsigned short* __restrict__ hb_out,
                                                    const float* __restrict__ q_s_next,
                                                    const float* __restrict__ q_d_next,
                                                    float4* __restrict__ als4,
                                                    float4* __restrict__ ald4,
                                                    int M) {
    __shared__ __align__(16) unsigned short As[64 * 136];
    __shared__ __align__(16) unsigned short Bs[128 * 136];
    int tid = threadIdx.x;
    int m0 = blockIdx.x << 6;
    int wave = tid >> 6, lane = tid & 63;
    int lr = lane & 15, lg = lane >> 4;

    const uint4 zero4 = make_uint4(0, 0, 0, 0);
#pragma unroll 1
    for (int rep = 0; rep < REPS; ++rep) {
        if (REPS > 1) __syncthreads();       // guard LDS reuse across reps
        f32x4 acc[8] = {};
        for (int kc = 0; kc < 4; kc++) {
#pragma unroll
            for (int p = 0; p < 4; p++) {        // A: 64 rows x 16 kg
                int i = p * 256 + tid;
                int row = i >> 4, kg = i & 15;
                int arow = m0 + row;
                uint4 av = (arow < M) ? *(const uint4*)(z + (size_t)arow * 512 + kc * 128 + kg * 8) : zero4;
                *(uint4*)&As[row * 136 + kg * 8] = av;
            }
#pragma unroll
            for (int p = 0; p < 8; p++) {        // B: 128 rows x 16 kg
                int i = p * 256 + tid;
                int row = i >> 4, kg = i & 15;
                uint4 bv = *(const uint4*)(wt2_l + (size_t)row * 512 + kc * 128 + kg * 8);
                *(uint4*)&Bs[row * 136 + kg * 8] = bv;
            }
            __syncthreads();
#pragma unroll
            for (int ks = 0; ks < 4; ks++) {
                bf16x8 af = *(const bf16x8*)&As[(wave * 16 + lr) * 136 + ks * 32 + lg * 8];
#pragma unroll
                for (int nt = 0; nt < 8; nt++) {
                    bf16x8 bf_ = *(const bf16x8*)&Bs[(nt * 16 + lr) * 136 + ks * 32 + lg * 8];
                    acc[nt] = __builtin_amdgcn_mfma_f32_16x16x32_bf16(af, bf_, acc[nt], 0, 0, 0);
                }
            }
            __syncthreads();
        }

        // epilogue: bias + LN + relu + residual (+ next-layer alpha)
        float bg[8], lnw[8], lnb[8];
#pragma unroll
        for (int nt = 0; nt < 8; nt++) {
            int col = nt * 16 + lr;
            bg[nt] = b_gat[col]; lnw[nt] = ln_w[col]; lnb[nt] = ln_b[col];
        }
        const bool do_alpha = (LYR + 1 < NLAYER);
        float4 qs4[8], qd4[8];
        if (do_alpha) {
#pragma unroll
            for (int nt = 0; nt < 8; nt++) {
                int col = nt * 16 + lr;
                qs4[nt] = *(const float4*)(q_s_next + (size_t)col * 4);
                qd4[nt] = *(const float4*)(q_d_next + (size_t)col * 4);
            }
        }
#pragma unroll
        for (int r = 0; r < 4; r++) {
            int row = m0 + wave * 16 + lg * 4 + r;
            bool valid = (row < M);
            float g[8];
            float s = 0.f;
#pragma unroll
            for (int nt = 0; nt < 8; nt++) { g[nt] = acc[nt][r] + bg[nt]; s += g[nt]; }
#pragma unroll
            for (int off = 1; off < 16; off <<= 1) s += __shfl_xor(s, off);
            float mu = s * (1.f / 128.f);
            float s2 = 0.f;
#pragma unroll
            for (int nt = 0; nt < 8; nt++) { float d = g[nt] - mu; s2 += d * d; }
#pragma unroll
            for (int off = 1; off < 16; off <<= 1) s2 += __shfl_xor(s2, off);
            float rstd = rsqrtf(s2 * (1.f / 128.f) + LN_EPS);
            float o[8];
#pragma unroll
            for (int nt = 0; nt < 8; nt++) {
                int col = nt * 16 + lr;
                float hv = valid ? b2f(hb_in[(size_t)row * 128 + col]) : 0.f;
                o[nt] = fmaxf((g[nt] - mu) * rstd * lnw[nt] + lnb[nt], 0.f) + hv;
                if (valid) hb_out[(size_t)row * 128 + col] = f2b(o[nt]);
            }
            if (do_alpha) {
                float ps[4] = {}, pd[4] = {};
#pragma unroll
                for (int nt = 0; nt < 8; nt++) {
                    ps[0] += o[nt] * qs4[nt].x; pd[0] += o[nt] * qd4[nt].x;
                    ps[1] += o[nt] * qs4[nt].y; pd[1] += o[nt] * qd4[nt].y;
                    ps[2] += o[nt] * qs4[nt].z; pd[2] += o[nt] * qd4[nt].z;
                    ps[3] += o[nt] * qs4[nt].w; pd[3] += o[nt] * qd4[nt].w;
                }
#pragma unroll
                for (int off = 1; off < 16; off <<= 1) {
#pragma unroll
                    for (int hh_ = 0; hh_ < 4; hh_++) {
                        ps[hh_] += __shfl_xor(ps[hh_], off);
                        pd[hh_] += __shfl_xor(pd[hh_], off);
                    }
                }
                if (lr == 0 && valid) {
                    als4[row] = make_float4(ps[0], ps[1], ps[2], ps[3]);
                    ald4[row] = make_float4(pd[0], pd[1], pd[2], pd[3]);
                }
            }
        }
    }
}

// ---------------------------------------------------------------------------
// Fused pooling + tail per graph (h is bf16).
// REPS>1: diagnostic replay (idempotent — rewrites identical out values).
// ---------------------------------------------------------------------------
__device__ int lower_bound_dev(const int* a, int n, int v) {
    int lo = 0, hi = n;
    while (lo < hi) { int mid = (lo + hi) >> 1; if (a[mid] < v) lo = mid + 1; else hi = mid; }
    return lo;
}

template<int REPS>
__global__ __launch_bounds__(512) void pooltail_kernel(
    const unsigned short* __restrict__ h, const int* __restrict__ batch,
    const float* __restrict__ tda,
    const float* __restrict__ w_t1, const float* __restrict__ b_t1,
    const float* __restrict__ w_t2, const float* __restrict__ b_t2,
    const float* __restrict__ w_sh1, const float* __restrict__ b_sh1,
    const float* __restrict__ w_sh2, const float* __restrict__ b_sh2,
    const float* __restrict__ w_h1, const float* __restrict__ b_h1,
    const float* __restrict__ w_h2, const float* __restrict__ b_h2,
    float* __restrict__ out) {
    __shared__ float ssum[4][128];
    __shared__ float smax[4][128];
    __shared__ int bounds[2];
    __shared__ float comb[320];
    __shared__ float tr[F_TDA];
    __shared__ float t1[64];
    __shared__ float s1o[256];
    __shared__ float s2o[128];
    __shared__ float prods[NTASK * 64];
    int g = blockIdx.x, tid = threadIdx.x;

#pragma unroll 1
    for (int rep = 0; rep < REPS; ++rep) {
        if (REPS > 1) __syncthreads();       // guard LDS reuse across reps
        if (tid < 2) bounds[tid] = lower_bound_dev(batch, N_NODES, g + tid);
        if (tid >= 2 && tid - 2 < F_TDA) tr[tid - 2] = tda[g * F_TDA + (tid - 2)];
        __syncthreads();
        int lo = bounds[0], hi = bounds[1];
        int q = tid >> 7, d = tid & 127;
        float s = 0.f, m = -1e30f;
        for (int i = lo + q; i < hi; i += 4) {
            float v = b2f(h[(size_t)i * DIM + d]);
            s += v; m = fmaxf(m, v);
        }
        ssum[q][d] = s; smax[q][d] = m;
        __syncthreads();
        if (tid < 128) {
            float S = ssum[0][d] + ssum[1][d] + ssum[2][d] + ssum[3][d];
            float M = fmaxf(fmaxf(smax[0][d], smax[1][d]), fmaxf(smax[2][d], smax[3][d]));
            int cnt = hi - lo;
            comb[d] = S / fmaxf((float)cnt, 1.f);
            comb[128 + d] = (cnt > 0) ? M : 0.f;
        } else if (tid >= 128 && tid < 192) {
            int j = tid - 128;
            float a = b_t1[j];
#pragma unroll
            for (int k = 0; k < F_TDA; k++) a += tr[k] * w_t1[k * 64 + j];
            t1[j] = fmaxf(a, 0.f);
        }
        __syncthreads();
        if (tid < 64) {
            float a = b_t2[tid];
#pragma unroll
            for (int k = 0; k < 64; k++) a += t1[k] * w_t2[k * 64 + tid];
            comb[256 + tid] = fmaxf(a, 0.f);
        }
        __syncthreads();
        if (tid < 256) {
            float a = b_sh1[tid];
            for (int k = 0; k < 320; k++) a += comb[k] * w_sh1[k * 256 + tid];
            s1o[tid] = fmaxf(a, 0.f);
        }
        __syncthreads();
        if (tid < 128) {
            float a = b_sh2[tid];
            for (int k = 0; k < 256; k++) a += s1o[k] * w_sh2[k * 128 + tid];
            s2o[tid] = fmaxf(a, 0.f);
        }
        __syncthreads();
        if (tid < NTASK * 64) {
            int t = tid >> 6, k = tid & 63;
            float a = b_h1[t * 64 + k];
#pragma unroll 16
            for (int dd = 0; dd < 128; dd++) a += s2o[dd] * w_h1[(size_t)t * 8192 + dd * 64 + k];
            prods[tid] = fmaxf(a, 0.f) * w_h2[t * 64 + k];
        }
        __syncthreads();
        if (tid < NTASK) {
            float p = b_h2[tid];
#pragma unroll 16
            for (int k = 0; k < 64; k++) p += prods[tid * 64 + k];
            out[tid * 256 + g] = p;
        }
    }
}

// ---------------------------------------------------------------------------
extern "C" void kernel_launch(void* const* d_in, const int* in_sizes, int n_in,
                              void* d_out, int out_size, void* d_ws, size_t ws_size,
                              hipStream_t stream) {
    const float* x        = (const float*)d_in[0];
    const int*   edge_idx = (const int*)  d_in[1];
    const int*   batch    = (const int*)  d_in[2];
    const float* tda      = (const float*)d_in[3];
    const float* w_in     = (const float*)d_in[4];
    const float* b_in     = (const float*)d_in[5];
    const float* w_gat    = (const float*)d_in[6];
    const float* a_src    = (const float*)d_in[7];
    const float* a_dst    = (const float*)d_in[8];
    const float* b_gat    = (const float*)d_in[9];
    const float* ln_w     = (const float*)d_in[10];
    const float* ln_b     = (const float*)d_in[11];
    const float* w_tda1   = (const float*)d_in[12];
    const float* b_tda1   = (const float*)d_in[13];
    const float* w_tda2   = (const float*)d_in[14];
    const float* b_tda2   = (const float*)d_in[15];
    const float* w_sh1    = (const float*)d_in[16];
    const float* b_sh1    = (const float*)d_in[17];
    const float* w_sh2    = (const float*)d_in[18];
    const float* b_sh2    = (const float*)d_in[19];
    const float* w_h1     = (const float*)d_in[20];
    const float* b_h1     = (const float*)d_in[21];
    const float* w_h2     = (const float*)d_in[22];
    const float* b_h2     = (const float*)d_in[23];
    float* out = (float*)d_out;

    size_t off = 0;
    auto alloc = [&](size_t bytes) -> void* {
        void* p = (char*)d_ws + off;
        off += (bytes + 255) & ~(size_t)255;
        return p;
    };
    unsigned short* hb_a   = (unsigned short*)alloc((size_t)N_NODES * DIM * 2);
    unsigned short* hb_b   = (unsigned short*)alloc((size_t)N_NODES * DIM * 2);
    unsigned short* z      = (unsigned short*)alloc((size_t)N_NODES * 512 * 2);
    unsigned short* wt2    = (unsigned short*)alloc((size_t)NLAYER * 128 * 512 * 2);
    float*          q_s    = (float*)alloc((size_t)NLAYER * 128 * 4 * 4);
    float*          q_d    = (float*)alloc((size_t)NLAYER * 128 * 4 * 4);
    float4*         als4   = (float4*)alloc((size_t)N_NODES * 16);
    float4*         ald4   = (float4*)alloc((size_t)N_NODES * 16);
    int*            degs   = (int*)  alloc((size_t)N_NODES * 4);
    int*            csrsrc = (int*)  alloc((size_t)N_NODES * CSR_CAP * 4);

    // qprep also zeroes degs (blocks 1152..1171) — no separate memset
    qprep_kernel<<<1172, 256, 0, stream>>>(w_gat, a_src, a_dst, wt2, q_s, q_d, degs);

    int sb = (E_TOTAL + 1023) / 1024;   // 333
    prep_kernel<<<2500 + sb, 256, 0, stream>>>(x, w_in, b_in, hb_a, q_s, q_d,
                                               als4, ald4, edge_idx, degs, csrsrc);

    int ab = (N_NODES + 3) / 4;
    int gb = (N_NODES + 63) / 64;
    // layer 0: hb_a -> hb_b
    agg2_kernel<0, 1><<<ab, 256, 0, stream>>>(hb_a, als4, ald4, degs, csrsrc, z);
    zgemm_kernel<0, 1><<<gb, 256, 0, stream>>>(z, wt2,
        b_gat, ln_w, ln_b, hb_a, hb_b, q_s + 512, q_d + 512, als4, ald4, N_NODES);
    // layer 1: hb_b -> hb_a
    agg2_kernel<1, 1><<<ab, 256, 0, stream>>>(hb_b, als4, ald4, degs, csrsrc, z);
    zgemm_kernel<1, 1><<<gb, 256, 0, stream>>>(z, wt2 + 65536,
        b_gat + DIM, ln_w + DIM, ln_b + DIM, hb_b, hb_a, q_s + 1024, q_d + 1024,
        als4, ald4, N_NODES);
    // layer 2: hb_a -> hb_b
    // DIAGNOSTIC (R3): REPS>1 on the three idempotent kernels to surface
    // their counters above the 44us harness fills in rocprof top-5.
    agg2_kernel<2, 4><<<ab, 256, 0, stream>>>(hb_a, als4, ald4, degs, csrsrc, z);
    zgemm_kernel<2, 12><<<gb, 256, 0, stream>>>(z, wt2 + 131072,
        b_gat + 2 * DIM, ln_w + 2 * DIM, ln_b + 2 * DIM, hb_a, hb_b,
        nullptr, nullptr, als4, ald4, N_NODES);

    pooltail_kernel<8><<<N_GRAPHS, 512, 0, stream>>>(
        hb_b, batch, tda, w_tda1, b_tda1, w_tda2, b_tda2,
        w_sh1, b_sh1, w_sh2, b_sh2, w_h1, b_h1, w_h2, b_h2, out);
}

// Round 5
// 510.036 us; speedup vs baseline: 1.4109x; 1.4109x over previous
//
#include <hip/hip_runtime.h>
#include <hip/hip_bf16.h>
#include <cstdint>
#include <cstddef>

// Problem constants (match reference)
#define N_NODES  20000
#define N_EDGES  320000
#define E_TOTAL  (N_EDGES + N_NODES)   // with self loops = 340000
#define N_GRAPHS 256
#define F_NODE   11
#define F_TDA    30
#define DIM      128
#define NHEAD    4
#define NLAYER   3
#define NTASK    6
#define NEG_SLOPE 0.2f
#define LN_EPS   1e-5f
#define CSR_CAP  64   // fixed per-node capacity; deg ~ Poisson(17), P(>64) ~ 0

typedef short bf16x8 __attribute__((ext_vector_type(8)));
typedef float f32x4  __attribute__((ext_vector_type(4)));
typedef float f32x2  __attribute__((ext_vector_type(2)));

__device__ inline unsigned short f2b(float f) {
    unsigned int u = __builtin_bit_cast(unsigned int, f);
    u += 0x7fffu + ((u >> 16) & 1u);
    return (unsigned short)(u >> 16);
}
__device__ inline float blo(unsigned int u) { return __builtin_bit_cast(float, u << 16); }
__device__ inline float bhi(unsigned int u) { return __builtin_bit_cast(float, u & 0xffff0000u); }
__device__ inline float b2f(unsigned short b) {
    return __builtin_bit_cast(float, ((unsigned int)b) << 16);
}

// ---------------------------------------------------------------------------
// qprep: [0,768) Wstack cast (k-permuted, 0.25 folded); [768,1152) q vectors;
// [1152,1172) zero degs. Runs BEFORE prep so prep can read q_s/q_d safely.
// ---------------------------------------------------------------------------
__global__ __launch_bounds__(256) void qprep_kernel(const float* __restrict__ w_gat,
                                                    const float* __restrict__ a_src,
                                                    const float* __restrict__ a_dst,
                                                    unsigned short* __restrict__ wt2,
                                                    float* __restrict__ q_s,
                                                    float* __restrict__ q_d,
                                                    int* __restrict__ degs) {
    int bx = blockIdx.x;
    int tid = threadIdx.x;
    if (bx < 768) {
        int i = bx * 256 + tid;              // over 3*128*512
        if (i >= NLAYER * 128 * 512) return;
        int l = i >> 16;
        int rem = i & 65535;
        int jcol = rem >> 9;
        int p = rem & 511;
        int lanep = p >> 3, j8 = p & 7;
        int hp = j8 >> 1, bb = j8 & 1;
        int d = lanep * 2 + bb;
        wt2[i] = f2b(w_gat[(size_t)l * 65536 + (size_t)d * 512 + hp * 128 + jcol] * 0.25f);
    } else if (bx < 1152) {
        int bx2 = bx - 768;                  // over 3*128
        int l = bx2 >> 7, k = bx2 & 127;
        int hh_ = tid >> 6, lane = tid & 63;
        int d0 = lane * 2;
        size_t wb = (size_t)l * 65536 + (size_t)k * 512 + hh_ * 128;
        size_t ab = (size_t)l * 512 + hh_ * 128;
        float ps = w_gat[wb + d0] * a_src[ab + d0] + w_gat[wb + d0 + 1] * a_src[ab + d0 + 1];
        float pd = w_gat[wb + d0] * a_dst[ab + d0] + w_gat[wb + d0 + 1] * a_dst[ab + d0 + 1];
#pragma unroll
        for (int off = 32; off; off >>= 1) { ps += __shfl_xor(ps, off); pd += __shfl_xor(pd, off); }
        if (lane == 0) {
            q_s[(size_t)(l * 128 + k) * 4 + hh_] = ps;
            q_d[(size_t)(l * 128 + k) * 4 + hh_] = pd;
        }
    } else {
        int i0 = (bx - 1152) * 1024 + tid;
#pragma unroll
        for (int r = 0; r < 4; r++) {
            int i = i0 + r * 256;
            if (i < N_NODES) degs[i] = 0;
        }
    }
}

// ---------------------------------------------------------------------------
// prep_proj: fat projection (8 nodes/block) + layer-0 alpha. Idempotent —
// REPS>1 is a diagnostic replay to surface this dispatch above the 44us
// harness fills in rocprof top-5 (dur/REPS = per-rep time).
// ---------------------------------------------------------------------------
template<int REPS>
__global__ __launch_bounds__(256) void prep_proj_kernel(const float* __restrict__ x,
                                                        const float* __restrict__ w,
                                                        const float* __restrict__ b,
                                                        unsigned short* __restrict__ h_bf,
                                                        const float* __restrict__ q_s,
                                                        const float* __restrict__ q_d,
                                                        float4* __restrict__ als4,
                                                        float4* __restrict__ ald4) {
    int bx = blockIdx.x;
    int tid = threadIdx.x;
    __shared__ float xr[8][F_NODE];
    __shared__ float vbuf[8][128];
    __shared__ float qs_t[512];
    __shared__ float qd_t[512];
#pragma unroll 1
    for (int rep = 0; rep < REPS; ++rep) {
        if (REPS > 1) __syncthreads();
        qs_t[tid] = q_s[tid]; qs_t[256 + tid] = q_s[256 + tid];
        qd_t[tid] = q_d[tid]; qd_t[256 + tid] = q_d[256 + tid];
        if (tid < 8 * F_NODE) {
            int nl = tid / F_NODE, k = tid % F_NODE;
            xr[nl][k] = x[(size_t)(bx * 8 + nl) * F_NODE + k];
        }
        __syncthreads();
        int d = tid & 127;
        int halfsel = tid >> 7;
#pragma unroll
        for (int p = 0; p < 4; p++) {
            int nl = p * 2 + halfsel;
            float acc = b[d];
#pragma unroll
            for (int k = 0; k < F_NODE; k++) acc += xr[nl][k] * w[k * DIM + d];
            float v = fmaxf(acc, 0.f);
            h_bf[(size_t)(bx * 8 + nl) * DIM + d] = f2b(v);
            vbuf[nl][d] = v;
        }
        __syncthreads();
        int wave = tid >> 6, lane = tid & 63;
#pragma unroll
        for (int t = 0; t < 2; t++) {
            int nl = wave * 2 + t;
            int n = bx * 8 + nl;
            float2 v2 = *(const float2*)&vbuf[nl][2 * lane];
            int k4 = 2 * lane * 4;
            float ps[4], pd[4];
#pragma unroll
            for (int hh_ = 0; hh_ < 4; hh_++) {
                ps[hh_] = v2.x * qs_t[k4 + hh_] + v2.y * qs_t[k4 + 4 + hh_];
                pd[hh_] = v2.x * qd_t[k4 + hh_] + v2.y * qd_t[k4 + 4 + hh_];
            }
#pragma unroll
            for (int off = 32; off; off >>= 1) {
#pragma unroll
                for (int hh_ = 0; hh_ < 4; hh_++) {
                    ps[hh_] += __shfl_xor(ps[hh_], off);
                    pd[hh_] += __shfl_xor(pd[hh_], off);
                }
            }
            if (lane == 0) {
                als4[n] = make_float4(ps[0], ps[1], ps[2], ps[3]);
                ald4[n] = make_float4(pd[0], pd[1], pd[2], pd[3]);
            }
        }
    }
}

// ---------------------------------------------------------------------------
// prep_scat: fixed-capacity CSR scatter, 4 edges/thread. NOT idempotent
// (atomics) — never replayed.
// ---------------------------------------------------------------------------
__global__ __launch_bounds__(256) void prep_scat_kernel(const int* __restrict__ edge_index,
                                                        int* __restrict__ degs,
                                                        int* __restrict__ csr_src) {
    int base = blockIdx.x * 1024;
    int tid = threadIdx.x;
#pragma unroll
    for (int k = 0; k < 4; k++) {
        int e = base + k * 256 + tid;
        if (e < E_TOTAL) {
            int s, d;
            if (e < N_EDGES) { s = edge_index[e]; d = edge_index[N_EDGES + e]; }
            else             { s = e - N_EDGES;   d = s; }
            int pos = atomicAdd(&degs[d], 1);
            if (pos < CSR_CAP) csr_src[d * CSR_CAP + pos] = s;
        }
    }
}

// ---------------------------------------------------------------------------
// h-space aggregation (R15/R17-proven structure). Wave per node; lane owns
// feature pair (2*lane, 2*lane+1) for all 4 heads. REPS: diagnostic replay.
// ---------------------------------------------------------------------------
template<int LYR, int REPS>
__global__ __launch_bounds__(256) void agg2_kernel(const unsigned short* __restrict__ h_bf,
                                                   const float4* __restrict__ als4,
                                                   const float4* __restrict__ ald4,
                                                   const int* __restrict__ degs,
                                                   const int* __restrict__ csr_src,
                                                   unsigned short* __restrict__ z) {
    int wave = threadIdx.x >> 6, lane = threadIdx.x & 63;
    int n = blockIdx.x * 4 + wave;
    if (n >= N_NODES) return;

    int deg = degs[n];
    const int* __restrict__ srcp = csr_src + (size_t)n * CSR_CAP;
    const unsigned int* __restrict__ h32 = (const unsigned int*)h_bf;
    const float* __restrict__ als_f = (const float*)als4;
    float4 ad = ald4[n];

    int l4 = lane & 3;                   // head this lane's w-computation covers
    int le = (lane >> 2) & 3;            // edge-in-batch this lane covers
    float adh = (l4 == 0) ? ad.x : ((l4 == 1) ? ad.y : ((l4 == 2) ? ad.z : ad.w));

#pragma unroll 1
    for (int rep = 0; rep < REPS; ++rep) {
        f32x2 acc2[4] = {};
        float lsOwn = 0.f;

        int s0 = 0, s1 = 0, s2 = 0, s3 = 0;
        if (deg >= 4) { s0 = srcp[0]; s1 = srcp[1]; s2 = srcp[2]; s3 = srcp[3]; }
        int e = 0;
        for (; e + 4 <= deg; ) {
            int c0 = s0, c1 = s1, c2 = s2, c3 = s3;
            unsigned int hv0 = h32[(size_t)c0 * 64 + lane];
            unsigned int hv1 = h32[(size_t)c1 * 64 + lane];
            unsigned int hv2 = h32[(size_t)c2 * 64 + lane];
            unsigned int hv3 = h32[(size_t)c3 * 64 + lane];
            int se = (le == 0) ? c0 : ((le == 1) ? c1 : ((le == 2) ? c2 : c3));
            float a = als_f[(size_t)se * 4 + l4];
            int en = e + 4;
            if (en + 4 <= deg) { s0 = srcp[en]; s1 = srcp[en + 1]; s2 = srcp[en + 2]; s3 = srcp[en + 3]; }
            float v = a + adh;
            v = fmaxf(v, NEG_SLOPE * v);
            float w = __expf(fminf(v, 60.f));
            lsOwn += w;
            float wv[16];
#pragma unroll
            for (int j = 0; j < 16; j++) wv[j] = __shfl(w, j);
            unsigned int hv[4] = { hv0, hv1, hv2, hv3 };
#pragma unroll
            for (int j = 0; j < 4; j++) {
                f32x2 f; f.x = blo(hv[j]); f.y = bhi(hv[j]);
                acc2[0] += wv[j * 4 + 0] * f;
                acc2[1] += wv[j * 4 + 1] * f;
                acc2[2] += wv[j * 4 + 2] * f;
                acc2[3] += wv[j * 4 + 3] * f;
            }
            e = en;
        }
        float ls[4];
#pragma unroll
        for (int hh_ = 0; hh_ < 4; hh_++) {
            ls[hh_] = __shfl(lsOwn, hh_) + __shfl(lsOwn, 4 + hh_)
                    + __shfl(lsOwn, 8 + hh_) + __shfl(lsOwn, 12 + hh_);
        }
        for (; e < deg; e++) {
            int s = srcp[e];
            float4 a4 = als4[s];
            unsigned int vv = h32[(size_t)s * 64 + lane];
            f32x2 f; f.x = blo(vv); f.y = bhi(vv);
#pragma unroll
            for (int hh_ = 0; hh_ < 4; hh_++) {
                float v = (&a4.x)[hh_] + (&ad.x)[hh_];
                v = (v > 0.f) ? v : NEG_SLOPE * v;
                float w = __expf(fminf(v, 60.f));
                ls[hh_] += w;
                acc2[hh_] += w * f;
            }
        }
        uint4 pb;
        unsigned int* pc = &pb.x;
#pragma unroll
        for (int hh_ = 0; hh_ < 4; hh_++) {
            float il = 1.f / ls[hh_];
            pc[hh_] = (unsigned)f2b(acc2[hh_].x * il) | ((unsigned)f2b(acc2[hh_].y * il) << 16);
        }
        *(uint4*)(z + (size_t)n * 512 + lane * 8) = pb;
    }
}

// ---------------------------------------------------------------------------
// zgemm v2 (R4): out = z[M,512] @ wt2[128,512]^T, fused bias + LN + ReLU +
// bf16 residual + next-layer alpha.
// R4 change: 512 threads / 8 waves (was 256/4) — R4 counters showed 7%
// occupancy, MfmaUtil 5.5%: latency-starved at 1.2 waves/SIMD. Waves now
// split N: wave=(msub,nh) computes rows msub*16.., cols nh*64..+63 (4 MFMA
// tiles). LN/alpha stats cross the two N-halves via small LDS reduce
// (sum/sumsq form). Staging pattern unchanged, spread over 512 threads.
// REPS: diagnostic replay (idempotent for LYR=2: no alpha writes).
// ---------------------------------------------------------------------------
template<int LYR, int REPS>
__global__ __launch_bounds__(512) void zgemm_kernel(const unsigned short* __restrict__ z,
                                                    const unsigned short* __restrict__ wt2_l,
                                                    const float* __restrict__ b_gat,
                                                    const float* __restrict__ ln_w,
                                                    const float* __restrict__ ln_b,
                                                    const unsigned short* __restrict__ hb_in,
                                                    unsigned short* __restrict__ hb_out,
                                                    const float* __restrict__ q_s_next,
                                                    const float* __restrict__ q_d_next,
                                                    float4* __restrict__ als4,
                                                    float4* __restrict__ ald4,
                                                    int M) {
    __shared__ __align__(16) unsigned short As[64 * 136];
    __shared__ __align__(16) unsigned short Bs[128 * 136];
    __shared__ float redS[2][4][16];
    __shared__ float redQ[2][4][16];
    __shared__ float redPS[2][4][16][4];
    __shared__ float redPD[2][4][16][4];
    int tid = threadIdx.x;
    int m0 = blockIdx.x << 6;
    int wave = tid >> 6, lane = tid & 63;
    int lr = lane & 15, lg = lane >> 4;
    int msub = wave & 3, nh = wave >> 2;

    const uint4 zero4 = make_uint4(0, 0, 0, 0);
#pragma unroll 1
    for (int rep = 0; rep < REPS; ++rep) {
        if (REPS > 1) __syncthreads();       // guard LDS reuse across reps
        f32x4 acc[4] = {};
        for (int kc = 0; kc < 4; kc++) {
#pragma unroll
            for (int p = 0; p < 2; p++) {        // A: 64 rows x 16 kg (512 thr)
                int i = p * 512 + tid;
                int row = i >> 4, kg = i & 15;
                int arow = m0 + row;
                uint4 av = (arow < M) ? *(const uint4*)(z + (size_t)arow * 512 + kc * 128 + kg * 8) : zero4;
                *(uint4*)&As[row * 136 + kg * 8] = av;
            }
#pragma unroll
            for (int p = 0; p < 4; p++) {        // B: 128 rows x 16 kg (512 thr)
                int i = p * 512 + tid;
                int row = i >> 4, kg = i & 15;
                uint4 bv = *(const uint4*)(wt2_l + (size_t)row * 512 + kc * 128 + kg * 8);
                *(uint4*)&Bs[row * 136 + kg * 8] = bv;
            }
            __syncthreads();
#pragma unroll
            for (int ks = 0; ks < 4; ks++) {
                bf16x8 af = *(const bf16x8*)&As[(msub * 16 + lr) * 136 + ks * 32 + lg * 8];
#pragma unroll
                for (int nt2 = 0; nt2 < 4; nt2++) {
                    int nt = nh * 4 + nt2;
                    bf16x8 bf_ = *(const bf16x8*)&Bs[(nt * 16 + lr) * 136 + ks * 32 + lg * 8];
                    acc[nt2] = __builtin_amdgcn_mfma_f32_16x16x32_bf16(af, bf_, acc[nt2], 0, 0, 0);
                }
            }
            __syncthreads();
        }

        // ---- epilogue: bias + LN (cross-half LDS reduce) + relu + residual ----
        float bg[4], lnw[4], lnb[4];
#pragma unroll
        for (int nt2 = 0; nt2 < 4; nt2++) {
            int col = nh * 64 + nt2 * 16 + lr;
            bg[nt2] = b_gat[col]; lnw[nt2] = ln_w[col]; lnb[nt2] = ln_b[col];
        }
        const bool do_alpha = (LYR + 1 < NLAYER);
        float4 qs4[4], qd4[4];
        if (do_alpha) {
#pragma unroll
            for (int nt2 = 0; nt2 < 4; nt2++) {
                int col = nh * 64 + nt2 * 16 + lr;
                qs4[nt2] = *(const float4*)(q_s_next + (size_t)col * 4);
                qd4[nt2] = *(const float4*)(q_d_next + (size_t)col * 4);
            }
        }
        float g[4][4];                       // [nt2][r]
#pragma unroll
        for (int nt2 = 0; nt2 < 4; nt2++)
#pragma unroll
            for (int r = 0; r < 4; r++) g[nt2][r] = acc[nt2][r] + bg[nt2];
        // per-row partial sum / sumsq over this wave's 64 cols
#pragma unroll
        for (int r = 0; r < 4; r++) {
            float s = 0.f, q = 0.f;
#pragma unroll
            for (int nt2 = 0; nt2 < 4; nt2++) { s += g[nt2][r]; q += g[nt2][r] * g[nt2][r]; }
#pragma unroll
            for (int off = 1; off < 16; off <<= 1) { s += __shfl_xor(s, off); q += __shfl_xor(q, off); }
            if (lr == 0) { redS[nh][msub][lg * 4 + r] = s; redQ[nh][msub][lg * 4 + r] = q; }
        }
        __syncthreads();
        float o[4][4];
#pragma unroll
        for (int r = 0; r < 4; r++) {
            int row = m0 + msub * 16 + lg * 4 + r;
            bool valid = (row < M);
            int ri = lg * 4 + r;
            float mu = (redS[0][msub][ri] + redS[1][msub][ri]) * (1.f / 128.f);
            float qq = (redQ[0][msub][ri] + redQ[1][msub][ri]) * (1.f / 128.f);
            float rstd = rsqrtf(fmaxf(qq - mu * mu, 0.f) + LN_EPS);
#pragma unroll
            for (int nt2 = 0; nt2 < 4; nt2++) {
                int col = nh * 64 + nt2 * 16 + lr;
                float hv = valid ? b2f(hb_in[(size_t)row * 128 + col]) : 0.f;
                o[nt2][r] = fmaxf((g[nt2][r] - mu) * rstd * lnw[nt2] + lnb[nt2], 0.f) + hv;
                if (valid) hb_out[(size_t)row * 128 + col] = f2b(o[nt2][r]);
            }
        }
        if (do_alpha) {
            float ps[4][4] = {}, pd[4][4] = {};   // [r][h]
#pragma unroll
            for (int r = 0; r < 4; r++)
#pragma unroll
                for (int nt2 = 0; nt2 < 4; nt2++) {
                    ps[r][0] += o[nt2][r] * qs4[nt2].x; pd[r][0] += o[nt2][r] * qd4[nt2].x;
                    ps[r][1] += o[nt2][r] * qs4[nt2].y; pd[r][1] += o[nt2][r] * qd4[nt2].y;
                    ps[r][2] += o[nt2][r] * qs4[nt2].z; pd[r][2] += o[nt2][r] * qd4[nt2].z;
                    ps[r][3] += o[nt2][r] * qs4[nt2].w; pd[r][3] += o[nt2][r] * qd4[nt2].w;
                }
#pragma unroll
            for (int r = 0; r < 4; r++)
#pragma unroll
                for (int off = 1; off < 16; off <<= 1)
#pragma unroll
                    for (int hh_ = 0; hh_ < 4; hh_++) {
                        ps[r][hh_] += __shfl_xor(ps[r][hh_], off);
                        pd[r][hh_] += __shfl_xor(pd[r][hh_], off);
                    }
            if (lr == 0) {
#pragma unroll
                for (int r = 0; r < 4; r++)
#pragma unroll
                    for (int hh_ = 0; hh_ < 4; hh_++) {
                        redPS[nh][msub][lg * 4 + r][hh_] = ps[r][hh_];
                        redPD[nh][msub][lg * 4 + r][hh_] = pd[r][hh_];
                    }
            }
            __syncthreads();
            if (nh == 0 && lr == 0) {
#pragma unroll
                for (int r = 0; r < 4; r++) {
                    int row = m0 + msub * 16 + lg * 4 + r;
                    int ri = lg * 4 + r;
                    if (row < M) {
                        als4[row] = make_float4(redPS[0][msub][ri][0] + redPS[1][msub][ri][0],
                                                redPS[0][msub][ri][1] + redPS[1][msub][ri][1],
                                                redPS[0][msub][ri][2] + redPS[1][msub][ri][2],
                                                redPS[0][msub][ri][3] + redPS[1][msub][ri][3]);
                        ald4[row] = make_float4(redPD[0][msub][ri][0] + redPD[1][msub][ri][0],
                                                redPD[0][msub][ri][1] + redPD[1][msub][ri][1],
                                                redPD[0][msub][ri][2] + redPD[1][msub][ri][2],
                                                redPD[0][msub][ri][3] + redPD[1][msub][ri][3]);
                    }
                }
            }
        }
    }
}

// ---------------------------------------------------------------------------
// Fused pooling + tail per graph (h is bf16). REPS: diagnostic replay.
// ---------------------------------------------------------------------------
__device__ int lower_bound_dev(const int* a, int n, int v) {
    int lo = 0, hi = n;
    while (lo < hi) { int mid = (lo + hi) >> 1; if (a[mid] < v) lo = mid + 1; else hi = mid; }
    return lo;
}

template<int REPS>
__global__ __launch_bounds__(512) void pooltail_kernel(
    const unsigned short* __restrict__ h, const int* __restrict__ batch,
    const float* __restrict__ tda,
    const float* __restrict__ w_t1, const float* __restrict__ b_t1,
    const float* __restrict__ w_t2, const float* __restrict__ b_t2,
    const float* __restrict__ w_sh1, const float* __restrict__ b_sh1,
    const float* __restrict__ w_sh2, const float* __restrict__ b_sh2,
    const float* __restrict__ w_h1, const float* __restrict__ b_h1,
    const float* __restrict__ w_h2, const float* __restrict__ b_h2,
    float* __restrict__ out) {
    __shared__ float ssum[4][128];
    __shared__ float smax[4][128];
    __shared__ int bounds[2];
    __shared__ float comb[320];
    __shared__ float tr[F_TDA];
    __shared__ float t1[64];
    __shared__ float s1o[256];
    __shared__ float s2o[128];
    __shared__ float prods[NTASK * 64];
    int g = blockIdx.x, tid = threadIdx.x;

#pragma unroll 1
    for (int rep = 0; rep < REPS; ++rep) {
        if (REPS > 1) __syncthreads();
        if (tid < 2) bounds[tid] = lower_bound_dev(batch, N_NODES, g + tid);
        if (tid >= 2 && tid - 2 < F_TDA) tr[tid - 2] = tda[g * F_TDA + (tid - 2)];
        __syncthreads();
        int lo = bounds[0], hi = bounds[1];
        int q = tid >> 7, d = tid & 127;
        float s = 0.f, m = -1e30f;
        for (int i = lo + q; i < hi; i += 4) {
            float v = b2f(h[(size_t)i * DIM + d]);
            s += v; m = fmaxf(m, v);
        }
        ssum[q][d] = s; smax[q][d] = m;
        __syncthreads();
        if (tid < 128) {
            float S = ssum[0][d] + ssum[1][d] + ssum[2][d] + ssum[3][d];
            float M = fmaxf(fmaxf(smax[0][d], smax[1][d]), fmaxf(smax[2][d], smax[3][d]));
            int cnt = hi - lo;
            comb[d] = S / fmaxf((float)cnt, 1.f);
            comb[128 + d] = (cnt > 0) ? M : 0.f;
        } else if (tid >= 128 && tid < 192) {
            int j = tid - 128;
            float a = b_t1[j];
#pragma unroll
            for (int k = 0; k < F_TDA; k++) a += tr[k] * w_t1[k * 64 + j];
            t1[j] = fmaxf(a, 0.f);
        }
        __syncthreads();
        if (tid < 64) {
            float a = b_t2[tid];
#pragma unroll
            for (int k = 0; k < 64; k++) a += t1[k] * w_t2[k * 64 + tid];
            comb[256 + tid] = fmaxf(a, 0.f);
        }
        __syncthreads();
        if (tid < 256) {
            float a = b_sh1[tid];
            for (int k = 0; k < 320; k++) a += comb[k] * w_sh1[k * 256 + tid];
            s1o[tid] = fmaxf(a, 0.f);
        }
        __syncthreads();
        if (tid < 128) {
            float a = b_sh2[tid];
            for (int k = 0; k < 256; k++) a += s1o[k] * w_sh2[k * 128 + tid];
            s2o[tid] = fmaxf(a, 0.f);
        }
        __syncthreads();
        if (tid < NTASK * 64) {
            int t = tid >> 6, k = tid & 63;
            float a = b_h1[t * 64 + k];
#pragma unroll 16
            for (int dd = 0; dd < 128; dd++) a += s2o[dd] * w_h1[(size_t)t * 8192 + dd * 64 + k];
            prods[tid] = fmaxf(a, 0.f) * w_h2[t * 64 + k];
        }
        __syncthreads();
        if (tid < NTASK) {
            float p = b_h2[tid];
#pragma unroll 16
            for (int k = 0; k < 64; k++) p += prods[tid * 64 + k];
            out[tid * 256 + g] = p;
        }
    }
}

// ---------------------------------------------------------------------------
extern "C" void kernel_launch(void* const* d_in, const int* in_sizes, int n_in,
                              void* d_out, int out_size, void* d_ws, size_t ws_size,
                              hipStream_t stream) {
    const float* x        = (const float*)d_in[0];
    const int*   edge_idx = (const int*)  d_in[1];
    const int*   batch    = (const int*)  d_in[2];
    const float* tda      = (const float*)d_in[3];
    const float* w_in     = (const float*)d_in[4];
    const float* b_in     = (const float*)d_in[5];
    const float* w_gat    = (const float*)d_in[6];
    const float* a_src    = (const float*)d_in[7];
    const float* a_dst    = (const float*)d_in[8];
    const float* b_gat    = (const float*)d_in[9];
    const float* ln_w     = (const float*)d_in[10];
    const float* ln_b     = (const float*)d_in[11];
    const float* w_tda1   = (const float*)d_in[12];
    const float* b_tda1   = (const float*)d_in[13];
    const float* w_tda2   = (const float*)d_in[14];
    const float* b_tda2   = (const float*)d_in[15];
    const float* w_sh1    = (const float*)d_in[16];
    const float* b_sh1    = (const float*)d_in[17];
    const float* w_sh2    = (const float*)d_in[18];
    const float* b_sh2    = (const float*)d_in[19];
    const float* w_h1     = (const float*)d_in[20];
    const float* b_h1     = (const float*)d_in[21];
    const float* w_h2     = (const float*)d_in[22];
    const float* b_h2     = (const float*)d_in[23];
    float* out = (float*)d_out;

    size_t off = 0;
    auto alloc = [&](size_t bytes) -> void* {
        void* p = (char*)d_ws + off;
        off += (bytes + 255) & ~(size_t)255;
        return p;
    };
    unsigned short* hb_a   = (unsigned short*)alloc((size_t)N_NODES * DIM * 2);
    unsigned short* hb_b   = (unsigned short*)alloc((size_t)N_NODES * DIM * 2);
    unsigned short* z      = (unsigned short*)alloc((size_t)N_NODES * 512 * 2);
    unsigned short* wt2    = (unsigned short*)alloc((size_t)NLAYER * 128 * 512 * 2);
    float*          q_s    = (float*)alloc((size_t)NLAYER * 128 * 4 * 4);
    float*          q_d    = (float*)alloc((size_t)NLAYER * 128 * 4 * 4);
    float4*         als4   = (float4*)alloc((size_t)N_NODES * 16);
    float4*         ald4   = (float4*)alloc((size_t)N_NODES * 16);
    int*            degs   = (int*)  alloc((size_t)N_NODES * 4);
    int*            csrsrc = (int*)  alloc((size_t)N_NODES * CSR_CAP * 4);

    // qprep also zeroes degs (blocks 1152..1171) — no separate memset
    qprep_kernel<<<1172, 256, 0, stream>>>(w_gat, a_src, a_dst, wt2, q_s, q_d, degs);

    // DIAGNOSTIC (R4): prep split; proj replayed 6x to surface its counters.
    prep_proj_kernel<6><<<2500, 256, 0, stream>>>(x, w_in, b_in, hb_a, q_s, q_d, als4, ald4);
    int sb = (E_TOTAL + 1023) / 1024;   // 333
    prep_scat_kernel<<<sb, 256, 0, stream>>>(edge_idx, degs, csrsrc);

    int ab = (N_NODES + 3) / 4;
    int gb = (N_NODES + 63) / 64;
    // layer 0: hb_a -> hb_b
    agg2_kernel<0, 1><<<ab, 256, 0, stream>>>(hb_a, als4, ald4, degs, csrsrc, z);
    zgemm_kernel<0, 1><<<gb, 512, 0, stream>>>(z, wt2,
        b_gat, ln_w, ln_b, hb_a, hb_b, q_s + 512, q_d + 512, als4, ald4, N_NODES);
    // layer 1: hb_b -> hb_a
    agg2_kernel<1, 1><<<ab, 256, 0, stream>>>(hb_b, als4, ald4, degs, csrsrc, z);
    zgemm_kernel<1, 1><<<gb, 512, 0, stream>>>(z, wt2 + 65536,
        b_gat + DIM, ln_w + DIM, ln_b + DIM, hb_b, hb_a, q_s + 1024, q_d + 1024,
        als4, ald4, N_NODES);
    // layer 2: hb_a -> hb_b
    agg2_kernel<2, 1><<<ab, 256, 0, stream>>>(hb_a, als4, ald4, degs, csrsrc, z);
    // DIAGNOSTIC (R4): zgemm<2> replayed 12x — T_zg_new = dur/12 read directly.
    zgemm_kernel<2, 12><<<gb, 512, 0, stream>>>(z, wt2 + 131072,
        b_gat + 2 * DIM, ln_w + 2 * DIM, ln_b + 2 * DIM, hb_a, hb_b,
        nullptr, nullptr, als4, ald4, N_NODES);

    pooltail_kernel<1><<<N_GRAPHS, 512, 0, stream>>>(
        hb_b, batch, tda, w_tda1, b_tda1, w_tda2, b_tda2,
        w_sh1, b_sh1, w_sh2, b_sh2, w_h1, b_h1, w_h2, b_h2, out);
}

// Round 7
// 498.608 us; speedup vs baseline: 1.4433x; 1.0229x over previous
//
#include <hip/hip_runtime.h>
#include <hip/hip_bf16.h>
#include <cstdint>
#include <cstddef>

// Problem constants (match reference)
#define N_NODES  20000
#define N_EDGES  320000
#define E_TOTAL  (N_EDGES + N_NODES)   // with self loops = 340000
#define N_GRAPHS 256
#define F_NODE   11
#define F_TDA    30
#define DIM      128
#define NHEAD    4
#define NLAYER   3
#define NTASK    6
#define NEG_SLOPE 0.2f
#define LN_EPS   1e-5f
#define CSR_CAP  64   // fixed per-node capacity; deg ~ Poisson(17), P(>64) ~ 0

typedef short bf16x8 __attribute__((ext_vector_type(8)));
typedef float f32x4  __attribute__((ext_vector_type(4)));
typedef float f32x2  __attribute__((ext_vector_type(2)));

__device__ inline unsigned short f2b(float f) {
    unsigned int u = __builtin_bit_cast(unsigned int, f);
    u += 0x7fffu + ((u >> 16) & 1u);
    return (unsigned short)(u >> 16);
}
__device__ inline float blo(unsigned int u) { return __builtin_bit_cast(float, u << 16); }
__device__ inline float bhi(unsigned int u) { return __builtin_bit_cast(float, u & 0xffff0000u); }
__device__ inline float b2f(unsigned short b) {
    return __builtin_bit_cast(float, ((unsigned int)b) << 16);
}

// ---------------------------------------------------------------------------
// qprep: [0,768) Wstack cast (k-permuted, 0.25 folded); [768,1152) q vectors;
// [1152,1172) zero degs. Runs BEFORE prep so prep can read q_s/q_d safely.
// ---------------------------------------------------------------------------
__global__ __launch_bounds__(256) void qprep_kernel(const float* __restrict__ w_gat,
                                                    const float* __restrict__ a_src,
                                                    const float* __restrict__ a_dst,
                                                    unsigned short* __restrict__ wt2,
                                                    float* __restrict__ q_s,
                                                    float* __restrict__ q_d,
                                                    int* __restrict__ degs) {
    int bx = blockIdx.x;
    int tid = threadIdx.x;
    if (bx < 768) {
        int i = bx * 256 + tid;              // over 3*128*512
        if (i >= NLAYER * 128 * 512) return;
        int l = i >> 16;
        int rem = i & 65535;
        int jcol = rem >> 9;
        int p = rem & 511;
        int lanep = p >> 3, j8 = p & 7;
        int hp = j8 >> 1, bb = j8 & 1;
        int d = lanep * 2 + bb;
        wt2[i] = f2b(w_gat[(size_t)l * 65536 + (size_t)d * 512 + hp * 128 + jcol] * 0.25f);
    } else if (bx < 1152) {
        int bx2 = bx - 768;                  // over 3*128
        int l = bx2 >> 7, k = bx2 & 127;
        int hh_ = tid >> 6, lane = tid & 63;
        int d0 = lane * 2;
        size_t wb = (size_t)l * 65536 + (size_t)k * 512 + hh_ * 128;
        size_t ab = (size_t)l * 512 + hh_ * 128;
        float ps = w_gat[wb + d0] * a_src[ab + d0] + w_gat[wb + d0 + 1] * a_src[ab + d0 + 1];
        float pd = w_gat[wb + d0] * a_dst[ab + d0] + w_gat[wb + d0 + 1] * a_dst[ab + d0 + 1];
#pragma unroll
        for (int off = 32; off; off >>= 1) { ps += __shfl_xor(ps, off); pd += __shfl_xor(pd, off); }
        if (lane == 0) {
            q_s[(size_t)(l * 128 + k) * 4 + hh_] = ps;
            q_d[(size_t)(l * 128 + k) * 4 + hh_] = pd;
        }
    } else {
        int i0 = (bx - 1152) * 1024 + tid;
#pragma unroll
        for (int r = 0; r < 4; r++) {
            int i = i0 + r * 256;
            if (i < N_NODES) degs[i] = 0;
        }
    }
}

// ---------------------------------------------------------------------------
// prep_proj: fat projection (8 nodes/block) + layer-0 alpha.
// ---------------------------------------------------------------------------
__global__ __launch_bounds__(256) void prep_proj_kernel(const float* __restrict__ x,
                                                        const float* __restrict__ w,
                                                        const float* __restrict__ b,
                                                        unsigned short* __restrict__ h_bf,
                                                        const float* __restrict__ q_s,
                                                        const float* __restrict__ q_d,
                                                        float4* __restrict__ als4,
                                                        float4* __restrict__ ald4) {
    int bx = blockIdx.x;
    int tid = threadIdx.x;
    __shared__ float xr[8][F_NODE];
    __shared__ float vbuf[8][128];
    __shared__ float qs_t[512];
    __shared__ float qd_t[512];
    qs_t[tid] = q_s[tid]; qs_t[256 + tid] = q_s[256 + tid];
    qd_t[tid] = q_d[tid]; qd_t[256 + tid] = q_d[256 + tid];
    if (tid < 8 * F_NODE) {
        int nl = tid / F_NODE, k = tid % F_NODE;
        xr[nl][k] = x[(size_t)(bx * 8 + nl) * F_NODE + k];
    }
    __syncthreads();
    int d = tid & 127;
    int halfsel = tid >> 7;
#pragma unroll
    for (int p = 0; p < 4; p++) {
        int nl = p * 2 + halfsel;
        float acc = b[d];
#pragma unroll
        for (int k = 0; k < F_NODE; k++) acc += xr[nl][k] * w[k * DIM + d];
        float v = fmaxf(acc, 0.f);
        h_bf[(size_t)(bx * 8 + nl) * DIM + d] = f2b(v);
        vbuf[nl][d] = v;
    }
    __syncthreads();
    int wave = tid >> 6, lane = tid & 63;
#pragma unroll
    for (int t = 0; t < 2; t++) {
        int nl = wave * 2 + t;
        int n = bx * 8 + nl;
        float2 v2 = *(const float2*)&vbuf[nl][2 * lane];
        int k4 = 2 * lane * 4;
        float ps[4], pd[4];
#pragma unroll
        for (int hh_ = 0; hh_ < 4; hh_++) {
            ps[hh_] = v2.x * qs_t[k4 + hh_] + v2.y * qs_t[k4 + 4 + hh_];
            pd[hh_] = v2.x * qd_t[k4 + hh_] + v2.y * qd_t[k4 + 4 + hh_];
        }
#pragma unroll
        for (int off = 32; off; off >>= 1) {
#pragma unroll
            for (int hh_ = 0; hh_ < 4; hh_++) {
                ps[hh_] += __shfl_xor(ps[hh_], off);
                pd[hh_] += __shfl_xor(pd[hh_], off);
            }
        }
        if (lane == 0) {
            als4[n] = make_float4(ps[0], ps[1], ps[2], ps[3]);
            ald4[n] = make_float4(pd[0], pd[1], pd[2], pd[3]);
        }
    }
}

// ---------------------------------------------------------------------------
// prep_scat: fixed-capacity CSR scatter, 4 edges/thread. NOT idempotent.
// ---------------------------------------------------------------------------
__global__ __launch_bounds__(256) void prep_scat_kernel(const int* __restrict__ edge_index,
                                                        int* __restrict__ degs,
                                                        int* __restrict__ csr_src) {
    int base = blockIdx.x * 1024;
    int tid = threadIdx.x;
#pragma unroll
    for (int k = 0; k < 4; k++) {
        int e = base + k * 256 + tid;
        if (e < E_TOTAL) {
            int s, d;
            if (e < N_EDGES) { s = edge_index[e]; d = edge_index[N_EDGES + e]; }
            else             { s = e - N_EDGES;   d = s; }
            int pos = atomicAdd(&degs[d], 1);
            if (pos < CSR_CAP) csr_src[d * CSR_CAP + pos] = s;
        }
    }
}

// ---------------------------------------------------------------------------
// h-space aggregation (R15/R17-proven structure). Wave per node; lane owns
// feature pair (2*lane, 2*lane+1) for all 4 heads.
// REPS>1: diagnostic replay (bit-idempotent: reads {h_bf,als4,ald4,degs,
// csr_src}, writes only z deterministically). R6: sole diagnostic this round
// so THIS dispatch tops the profile and we finally get agg2's counters.
// Pre-committed reads: VALUBusy>50% -> issue-bound; Occupancy<25% ->
// VGPR-limited; both low -> L3-latency-bound.
// ---------------------------------------------------------------------------
template<int LYR, int REPS>
__global__ __launch_bounds__(256) void agg2_kernel(const unsigned short* __restrict__ h_bf,
                                                   const float4* __restrict__ als4,
                                                   const float4* __restrict__ ald4,
                                                   const int* __restrict__ degs,
                                                   const int* __restrict__ csr_src,
                                                   unsigned short* __restrict__ z) {
    int wave = threadIdx.x >> 6, lane = threadIdx.x & 63;
    int n = blockIdx.x * 4 + wave;
    if (n >= N_NODES) return;

    int deg = degs[n];
    const int* __restrict__ srcp = csr_src + (size_t)n * CSR_CAP;
    const unsigned int* __restrict__ h32 = (const unsigned int*)h_bf;
    const float* __restrict__ als_f = (const float*)als4;
    float4 ad = ald4[n];

    int l4 = lane & 3;                   // head this lane's w-computation covers
    int le = (lane >> 2) & 3;            // edge-in-batch this lane covers
    float adh = (l4 == 0) ? ad.x : ((l4 == 1) ? ad.y : ((l4 == 2) ? ad.z : ad.w));

#pragma unroll 1
    for (int rep = 0; rep < REPS; ++rep) {
        f32x2 acc2[4] = {};
        float lsOwn = 0.f;

        int s0 = 0, s1 = 0, s2 = 0, s3 = 0;
        if (deg >= 4) { s0 = srcp[0]; s1 = srcp[1]; s2 = srcp[2]; s3 = srcp[3]; }
        int e = 0;
        for (; e + 4 <= deg; ) {
            int c0 = s0, c1 = s1, c2 = s2, c3 = s3;
            unsigned int hv0 = h32[(size_t)c0 * 64 + lane];
            unsigned int hv1 = h32[(size_t)c1 * 64 + lane];
            unsigned int hv2 = h32[(size_t)c2 * 64 + lane];
            unsigned int hv3 = h32[(size_t)c3 * 64 + lane];
            int se = (le == 0) ? c0 : ((le == 1) ? c1 : ((le == 2) ? c2 : c3));
            float a = als_f[(size_t)se * 4 + l4];
            int en = e + 4;
            if (en + 4 <= deg) { s0 = srcp[en]; s1 = srcp[en + 1]; s2 = srcp[en + 2]; s3 = srcp[en + 3]; }
            float v = a + adh;
            v = fmaxf(v, NEG_SLOPE * v);
            float w = __expf(fminf(v, 60.f));
            lsOwn += w;
            float wv[16];
#pragma unroll
            for (int j = 0; j < 16; j++) wv[j] = __shfl(w, j);
            unsigned int hv[4] = { hv0, hv1, hv2, hv3 };
#pragma unroll
            for (int j = 0; j < 4; j++) {
                f32x2 f; f.x = blo(hv[j]); f.y = bhi(hv[j]);
                acc2[0] += wv[j * 4 + 0] * f;
                acc2[1] += wv[j * 4 + 1] * f;
                acc2[2] += wv[j * 4 + 2] * f;
                acc2[3] += wv[j * 4 + 3] * f;
            }
            e = en;
        }
        float ls[4];
#pragma unroll
        for (int hh_ = 0; hh_ < 4; hh_++) {
            ls[hh_] = __shfl(lsOwn, hh_) + __shfl(lsOwn, 4 + hh_)
                    + __shfl(lsOwn, 8 + hh_) + __shfl(lsOwn, 12 + hh_);
        }
        for (; e < deg; e++) {
            int s = srcp[e];
            float4 a4 = als4[s];
            unsigned int vv = h32[(size_t)s * 64 + lane];
            f32x2 f; f.x = blo(vv); f.y = bhi(vv);
#pragma unroll
            for (int hh_ = 0; hh_ < 4; hh_++) {
                float v = (&a4.x)[hh_] + (&ad.x)[hh_];
                v = (v > 0.f) ? v : NEG_SLOPE * v;
                float w = __expf(fminf(v, 60.f));
                ls[hh_] += w;
                acc2[hh_] += w * f;
            }
        }
        uint4 pb;
        unsigned int* pc = &pb.x;
#pragma unroll
        for (int hh_ = 0; hh_ < 4; hh_++) {
            float il = 1.f / ls[hh_];
            pc[hh_] = (unsigned)f2b(acc2[hh_].x * il) | ((unsigned)f2b(acc2[hh_].y * il) << 16);
        }
        *(uint4*)(z + (size_t)n * 512 + lane * 8) = pb;
    }
}

// ---------------------------------------------------------------------------
// zgemm v2: out = z[M,512] @ wt2[128,512]^T, fused bias + LN + ReLU + bf16
// residual + next-layer alpha. 512 thr / 8 waves; wave=(msub,nh) computes
// 16 rows x 64 cols. Verified R5: 18.8 -> 14.0 us/rep.
// ---------------------------------------------------------------------------
template<int LYR, int REPS>
__global__ __launch_bounds__(512) void zgemm_kernel(const unsigned short* __restrict__ z,
                                                    const unsigned short* __restrict__ wt2_l,
                                                    const float* __restrict__ b_gat,
                                                    const float* __restrict__ ln_w,
                                                    const float* __restrict__ ln_b,
                                                    const unsigned short* __restrict__ hb_in,
                                                    unsigned short* __restrict__ hb_out,
                                                    const float* __restrict__ q_s_next,
                                                    const float* __restrict__ q_d_next,
                                                    float4* __restrict__ als4,
                                                    float4* __restrict__ ald4,
                                                    int M) {
    __shared__ __align__(16) unsigned short As[64 * 136];
    __shared__ __align__(16) unsigned short Bs[128 * 136];
    __shared__ float redS[2][4][16];
    __shared__ float redQ[2][4][16];
    __shared__ float redPS[2][4][16][4];
    __shared__ float redPD[2][4][16][4];
    int tid = threadIdx.x;
    int m0 = blockIdx.x << 6;
    int wave = tid >> 6, lane = tid & 63;
    int lr = lane & 15, lg = lane >> 4;
    int msub = wave & 3, nh = wave >> 2;

    const uint4 zero4 = make_uint4(0, 0, 0, 0);
#pragma unroll 1
    for (int rep = 0; rep < REPS; ++rep) {
        if (REPS > 1) __syncthreads();
        f32x4 acc[4] = {};
        for (int kc = 0; kc < 4; kc++) {
#pragma unroll
            for (int p = 0; p < 2; p++) {        // A: 64 rows x 16 kg (512 thr)
                int i = p * 512 + tid;
                int row = i >> 4, kg = i & 15;
                int arow = m0 + row;
                uint4 av = (arow < M) ? *(const uint4*)(z + (size_t)arow * 512 + kc * 128 + kg * 8) : zero4;
                *(uint4*)&As[row * 136 + kg * 8] = av;
            }
#pragma unroll
            for (int p = 0; p < 4; p++) {        // B: 128 rows x 16 kg (512 thr)
                int i = p * 512 + tid;
                int row = i >> 4, kg = i & 15;
                uint4 bv = *(const uint4*)(wt2_l + (size_t)row * 512 + kc * 128 + kg * 8);
                *(uint4*)&Bs[row * 136 + kg * 8] = bv;
            }
            __syncthreads();
#pragma unroll
            for (int ks = 0; ks < 4; ks++) {
                bf16x8 af = *(const bf16x8*)&As[(msub * 16 + lr) * 136 + ks * 32 + lg * 8];
#pragma unroll
                for (int nt2 = 0; nt2 < 4; nt2++) {
                    int nt = nh * 4 + nt2;
                    bf16x8 bf_ = *(const bf16x8*)&Bs[(nt * 16 + lr) * 136 + ks * 32 + lg * 8];
                    acc[nt2] = __builtin_amdgcn_mfma_f32_16x16x32_bf16(af, bf_, acc[nt2], 0, 0, 0);
                }
            }
            __syncthreads();
        }

        // ---- epilogue: bias + LN (cross-half LDS reduce) + relu + residual ----
        float bg[4], lnw[4], lnb[4];
#pragma unroll
        for (int nt2 = 0; nt2 < 4; nt2++) {
            int col = nh * 64 + nt2 * 16 + lr;
            bg[nt2] = b_gat[col]; lnw[nt2] = ln_w[col]; lnb[nt2] = ln_b[col];
        }
        const bool do_alpha = (LYR + 1 < NLAYER);
        float4 qs4[4], qd4[4];
        if (do_alpha) {
#pragma unroll
            for (int nt2 = 0; nt2 < 4; nt2++) {
                int col = nh * 64 + nt2 * 16 + lr;
                qs4[nt2] = *(const float4*)(q_s_next + (size_t)col * 4);
                qd4[nt2] = *(const float4*)(q_d_next + (size_t)col * 4);
            }
        }
        float g[4][4];                       // [nt2][r]
#pragma unroll
        for (int nt2 = 0; nt2 < 4; nt2++)
#pragma unroll
            for (int r = 0; r < 4; r++) g[nt2][r] = acc[nt2][r] + bg[nt2];
#pragma unroll
        for (int r = 0; r < 4; r++) {
            float s = 0.f, q = 0.f;
#pragma unroll
            for (int nt2 = 0; nt2 < 4; nt2++) { s += g[nt2][r]; q += g[nt2][r] * g[nt2][r]; }
#pragma unroll
            for (int off = 1; off < 16; off <<= 1) { s += __shfl_xor(s, off); q += __shfl_xor(q, off); }
            if (lr == 0) { redS[nh][msub][lg * 4 + r] = s; redQ[nh][msub][lg * 4 + r] = q; }
        }
        __syncthreads();
        float o[4][4];
#pragma unroll
        for (int r = 0; r < 4; r++) {
            int row = m0 + msub * 16 + lg * 4 + r;
            bool valid = (row < M);
            int ri = lg * 4 + r;
            float mu = (redS[0][msub][ri] + redS[1][msub][ri]) * (1.f / 128.f);
            float qq = (redQ[0][msub][ri] + redQ[1][msub][ri]) * (1.f / 128.f);
            float rstd = rsqrtf(fmaxf(qq - mu * mu, 0.f) + LN_EPS);
#pragma unroll
            for (int nt2 = 0; nt2 < 4; nt2++) {
                int col = nh * 64 + nt2 * 16 + lr;
                float hv = valid ? b2f(hb_in[(size_t)row * 128 + col]) : 0.f;
                o[nt2][r] = fmaxf((g[nt2][r] - mu) * rstd * lnw[nt2] + lnb[nt2], 0.f) + hv;
                if (valid) hb_out[(size_t)row * 128 + col] = f2b(o[nt2][r]);
            }
        }
        if (do_alpha) {
            float ps[4][4] = {}, pd[4][4] = {};   // [r][h]
#pragma unroll
            for (int r = 0; r < 4; r++)
#pragma unroll
                for (int nt2 = 0; nt2 < 4; nt2++) {
                    ps[r][0] += o[nt2][r] * qs4[nt2].x; pd[r][0] += o[nt2][r] * qd4[nt2].x;
                    ps[r][1] += o[nt2][r] * qs4[nt2].y; pd[r][1] += o[nt2][r] * qd4[nt2].y;
                    ps[r][2] += o[nt2][r] * qs4[nt2].z; pd[r][2] += o[nt2][r] * qd4[nt2].z;
                    ps[r][3] += o[nt2][r] * qs4[nt2].w; pd[r][3] += o[nt2][r] * qd4[nt2].w;
                }
#pragma unroll
            for (int r = 0; r < 4; r++)
#pragma unroll
                for (int off = 1; off < 16; off <<= 1)
#pragma unroll
                    for (int hh_ = 0; hh_ < 4; hh_++) {
                        ps[r][hh_] += __shfl_xor(ps[r][hh_], off);
                        pd[r][hh_] += __shfl_xor(pd[r][hh_], off);
                    }
            if (lr == 0) {
#pragma unroll
                for (int r = 0; r < 4; r++)
#pragma unroll
                    for (int hh_ = 0; hh_ < 4; hh_++) {
                        redPS[nh][msub][lg * 4 + r][hh_] = ps[r][hh_];
                        redPD[nh][msub][lg * 4 + r][hh_] = pd[r][hh_];
                    }
            }
            __syncthreads();
            if (nh == 0 && lr == 0) {
#pragma unroll
                for (int r = 0; r < 4; r++) {
                    int row = m0 + msub * 16 + lg * 4 + r;
                    int ri = lg * 4 + r;
                    if (row < M) {
                        als4[row] = make_float4(redPS[0][msub][ri][0] + redPS[1][msub][ri][0],
                                                redPS[0][msub][ri][1] + redPS[1][msub][ri][1],
                                                redPS[0][msub][ri][2] + redPS[1][msub][ri][2],
                                                redPS[0][msub][ri][3] + redPS[1][msub][ri][3]);
                        ald4[row] = make_float4(redPD[0][msub][ri][0] + redPD[1][msub][ri][0],
                                                redPD[0][msub][ri][1] + redPD[1][msub][ri][1],
                                                redPD[0][msub][ri][2] + redPD[1][msub][ri][2],
                                                redPD[0][msub][ri][3] + redPD[1][msub][ri][3]);
                    }
                }
            }
        }
    }
}

// ---------------------------------------------------------------------------
// pool4 (R6): per-graph pooling split 4 ways — block (g,q4) computes partial
// sum/max over its quarter of graph g's nodes. 4x the pooling parallelism of
// the old fused pooltail (which was 1 block/graph and latency-bound).
// ---------------------------------------------------------------------------
__device__ int lower_bound_dev(const int* a, int n, int v) {
    int lo = 0, hi = n;
    while (lo < hi) { int mid = (lo + hi) >> 1; if (a[mid] < v) lo = mid + 1; else hi = mid; }
    return lo;
}

__global__ __launch_bounds__(256) void pool4_kernel(const unsigned short* __restrict__ h,
                                                    const int* __restrict__ batch,
                                                    float* __restrict__ pool_ws) {
    int g = blockIdx.x >> 2, q4 = blockIdx.x & 3;
    int tid = threadIdx.x;
    __shared__ int bounds[2];
    __shared__ float psum[2][128];
    __shared__ float pmax[2][128];
    if (tid < 2) bounds[tid] = lower_bound_dev(batch, N_NODES, g + tid);
    __syncthreads();
    int lo = bounds[0], hi = bounds[1];
    int cnt = hi - lo;
    int per = (cnt + 3) >> 2;
    int beg = lo + q4 * per;
    int end = min(beg + per, hi);
    int rq = tid >> 7, d = tid & 127;
    float s = 0.f, m = -1e30f;
    for (int i = beg + rq; i < end; i += 2) {
        float v = b2f(h[(size_t)i * DIM + d]);
        s += v; m = fmaxf(m, v);
    }
    psum[rq][d] = s; pmax[rq][d] = m;
    __syncthreads();
    if (tid < 128) {
        float S = psum[0][d] + psum[1][d];
        float M = fmaxf(pmax[0][d], pmax[1][d]);
        pool_ws[(((size_t)g * 4 + q4) * 2 + 0) * 128 + d] = S;
        pool_ws[(((size_t)g * 4 + q4) * 2 + 1) * 128 + d] = M;
    }
}

// ---------------------------------------------------------------------------
// tail (R6): per-graph MLP tail; pooling phase replaced by reading the 4
// partials from pool_ws.
// ---------------------------------------------------------------------------
__global__ __launch_bounds__(512) void tail_kernel(
    const float* __restrict__ pool_ws, const int* __restrict__ batch,
    const float* __restrict__ tda,
    const float* __restrict__ w_t1, const float* __restrict__ b_t1,
    const float* __restrict__ w_t2, const float* __restrict__ b_t2,
    const float* __restrict__ w_sh1, const float* __restrict__ b_sh1,
    const float* __restrict__ w_sh2, const float* __restrict__ b_sh2,
    const float* __restrict__ w_h1, const float* __restrict__ b_h1,
    const float* __restrict__ w_h2, const float* __restrict__ b_h2,
    float* __restrict__ out) {
    __shared__ int bounds[2];
    __shared__ float comb[320];
    __shared__ float tr[F_TDA];
    __shared__ float t1[64];
    __shared__ float s1o[256];
    __shared__ float s2o[128];
    __shared__ float prods[NTASK * 64];
    int g = blockIdx.x, tid = threadIdx.x;

    if (tid < 2) bounds[tid] = lower_bound_dev(batch, N_NODES, g + tid);
    if (tid >= 2 && tid - 2 < F_TDA) tr[tid - 2] = tda[g * F_TDA + (tid - 2)];
    __syncthreads();
    int cnt = bounds[1] - bounds[0];
    if (tid < 128) {
        float S = 0.f, M = -1e30f;
#pragma unroll
        for (int q4 = 0; q4 < 4; q4++) {
            S += pool_ws[(((size_t)g * 4 + q4) * 2 + 0) * 128 + tid];
            M = fmaxf(M, pool_ws[(((size_t)g * 4 + q4) * 2 + 1) * 128 + tid]);
        }
        comb[tid] = S / fmaxf((float)cnt, 1.f);
        comb[128 + tid] = (cnt > 0) ? M : 0.f;
    } else if (tid >= 128 && tid < 192) {
        int j = tid - 128;
        float a = b_t1[j];
#pragma unroll
        for (int k = 0; k < F_TDA; k++) a += tr[k] * w_t1[k * 64 + j];
        t1[j] = fmaxf(a, 0.f);
    }
    __syncthreads();
    if (tid < 64) {
        float a = b_t2[tid];
#pragma unroll
        for (int k = 0; k < 64; k++) a += t1[k] * w_t2[k * 64 + tid];
        comb[256 + tid] = fmaxf(a, 0.f);
    }
    __syncthreads();
    if (tid < 256) {
        float a = b_sh1[tid];
        for (int k = 0; k < 320; k++) a += comb[k] * w_sh1[k * 256 + tid];
        s1o[tid] = fmaxf(a, 0.f);
    }
    __syncthreads();
    if (tid < 128) {
        float a = b_sh2[tid];
        for (int k = 0; k < 256; k++) a += s1o[k] * w_sh2[k * 128 + tid];
        s2o[tid] = fmaxf(a, 0.f);
    }
    __syncthreads();
    if (tid < NTASK * 64) {
        int t = tid >> 6, k = tid & 63;
        float a = b_h1[t * 64 + k];
#pragma unroll 16
        for (int dd = 0; dd < 128; dd++) a += s2o[dd] * w_h1[(size_t)t * 8192 + dd * 64 + k];
        prods[tid] = fmaxf(a, 0.f) * w_h2[t * 64 + k];
    }
    __syncthreads();
    if (tid < NTASK) {
        float p = b_h2[tid];
#pragma unroll 16
        for (int k = 0; k < 64; k++) p += prods[tid * 64 + k];
        out[tid * 256 + g] = p;
    }
}

// ---------------------------------------------------------------------------
extern "C" void kernel_launch(void* const* d_in, const int* in_sizes, int n_in,
                              void* d_out, int out_size, void* d_ws, size_t ws_size,
                              hipStream_t stream) {
    const float* x        = (const float*)d_in[0];
    const int*   edge_idx = (const int*)  d_in[1];
    const int*   batch    = (const int*)  d_in[2];
    const float* tda      = (const float*)d_in[3];
    const float* w_in     = (const float*)d_in[4];
    const float* b_in     = (const float*)d_in[5];
    const float* w_gat    = (const float*)d_in[6];
    const float* a_src    = (const float*)d_in[7];
    const float* a_dst    = (const float*)d_in[8];
    const float* b_gat    = (const float*)d_in[9];
    const float* ln_w     = (const float*)d_in[10];
    const float* ln_b     = (const float*)d_in[11];
    const float* w_tda1   = (const float*)d_in[12];
    const float* b_tda1   = (const float*)d_in[13];
    const float* w_tda2   = (const float*)d_in[14];
    const float* b_tda2   = (const float*)d_in[15];
    const float* w_sh1    = (const float*)d_in[16];
    const float* b_sh1    = (const float*)d_in[17];
    const float* w_sh2    = (const float*)d_in[18];
    const float* b_sh2    = (const float*)d_in[19];
    const float* w_h1     = (const float*)d_in[20];
    const float* b_h1     = (const float*)d_in[21];
    const float* w_h2     = (const float*)d_in[22];
    const float* b_h2     = (const float*)d_in[23];
    float* out = (float*)d_out;

    size_t off = 0;
    auto alloc = [&](size_t bytes) -> void* {
        void* p = (char*)d_ws + off;
        off += (bytes + 255) & ~(size_t)255;
        return p;
    };
    unsigned short* hb_a   = (unsigned short*)alloc((size_t)N_NODES * DIM * 2);
    unsigned short* hb_b   = (unsigned short*)alloc((size_t)N_NODES * DIM * 2);
    unsigned short* z      = (unsigned short*)alloc((size_t)N_NODES * 512 * 2);
    unsigned short* wt2    = (unsigned short*)alloc((size_t)NLAYER * 128 * 512 * 2);
    float*          q_s    = (float*)alloc((size_t)NLAYER * 128 * 4 * 4);
    float*          q_d    = (float*)alloc((size_t)NLAYER * 128 * 4 * 4);
    float4*         als4   = (float4*)alloc((size_t)N_NODES * 16);
    float4*         ald4   = (float4*)alloc((size_t)N_NODES * 16);
    int*            degs   = (int*)  alloc((size_t)N_NODES * 4);
    int*            csrsrc = (int*)  alloc((size_t)N_NODES * CSR_CAP * 4);
    float*          poolws = (float*)alloc((size_t)N_GRAPHS * 4 * 2 * 128 * 4);

    // qprep also zeroes degs (blocks 1152..1171) — no separate memset
    qprep_kernel<<<1172, 256, 0, stream>>>(w_gat, a_src, a_dst, wt2, q_s, q_d, degs);

    prep_proj_kernel<<<2500, 256, 0, stream>>>(x, w_in, b_in, hb_a, q_s, q_d, als4, ald4);
    int sb = (E_TOTAL + 1023) / 1024;   // 333
    prep_scat_kernel<<<sb, 256, 0, stream>>>(edge_idx, degs, csrsrc);

    int ab = (N_NODES + 3) / 4;
    int gb = (N_NODES + 63) / 64;
    // layer 0: hb_a -> hb_b
    agg2_kernel<0, 1><<<ab, 256, 0, stream>>>(hb_a, als4, ald4, degs, csrsrc, z);
    zgemm_kernel<0, 1><<<gb, 512, 0, stream>>>(z, wt2,
        b_gat, ln_w, ln_b, hb_a, hb_b, q_s + 512, q_d + 512, als4, ald4, N_NODES);
    // layer 1: hb_b -> hb_a
    agg2_kernel<1, 1><<<ab, 256, 0, stream>>>(hb_b, als4, ald4, degs, csrsrc, z);
    zgemm_kernel<1, 1><<<gb, 512, 0, stream>>>(z, wt2 + 65536,
        b_gat + DIM, ln_w + DIM, ln_b + DIM, hb_b, hb_a, q_s + 1024, q_d + 1024,
        als4, ald4, N_NODES);
    // layer 2: hb_a -> hb_b
    // DIAGNOSTIC (R6): agg2<2> replayed 12x — the SOLE amplified kernel this
    // round so its dispatch tops the profile. T_agg2 = dur/12; read counters.
    agg2_kernel<2, 12><<<ab, 256, 0, stream>>>(hb_a, als4, ald4, degs, csrsrc, z);
    zgemm_kernel<2, 1><<<gb, 512, 0, stream>>>(z, wt2 + 131072,
        b_gat + 2 * DIM, ln_w + 2 * DIM, ln_b + 2 * DIM, hb_a, hb_b,
        nullptr, nullptr, als4, ald4, N_NODES);

    pool4_kernel<<<N_GRAPHS * 4, 256, 0, stream>>>(hb_b, batch, poolws);
    tail_kernel<<<N_GRAPHS, 512, 0, stream>>>(
        poolws, batch, tda, w_tda1, b_tda1, w_tda2, b_tda2,
        w_sh1, b_sh1, w_sh2, b_sh2, w_h1, b_h1, w_h2, b_h2, out);
}

// Round 8
// 399.007 us; speedup vs baseline: 1.8035x; 1.2496x over previous
//
#include <hip/hip_runtime.h>
#include <hip/hip_bf16.h>
#include <cstdint>
#include <cstddef>

// Problem constants (match reference)
#define N_NODES  20000
#define N_EDGES  320000
#define E_TOTAL  (N_EDGES + N_NODES)   // with self loops = 340000
#define N_GRAPHS 256
#define F_NODE   11
#define F_TDA    30
#define DIM      128
#define NHEAD    4
#define NLAYER   3
#define NTASK    6
#define NEG_SLOPE 0.2f
#define LN_EPS   1e-5f
#define CSR_CAP  64   // fixed per-node capacity; deg ~ Poisson(17), P(>64) ~ 0

typedef short bf16x8 __attribute__((ext_vector_type(8)));
typedef float f32x4  __attribute__((ext_vector_type(4)));
typedef float f32x2  __attribute__((ext_vector_type(2)));

__device__ inline unsigned short f2b(float f) {
    unsigned int u = __builtin_bit_cast(unsigned int, f);
    u += 0x7fffu + ((u >> 16) & 1u);
    return (unsigned short)(u >> 16);
}
__device__ inline float blo(unsigned int u) { return __builtin_bit_cast(float, u << 16); }
__device__ inline float bhi(unsigned int u) { return __builtin_bit_cast(float, u & 0xffff0000u); }
__device__ inline float b2f(unsigned short b) {
    return __builtin_bit_cast(float, ((unsigned int)b) << 16);
}

// ---------------------------------------------------------------------------
// qprep: [0,768) Wstack cast (k-permuted, 0.25 folded); [768,1152) q vectors;
// [1152,1172) zero degs. Runs BEFORE prep so prep can read q_s/q_d safely.
// ---------------------------------------------------------------------------
__global__ __launch_bounds__(256) void qprep_kernel(const float* __restrict__ w_gat,
                                                    const float* __restrict__ a_src,
                                                    const float* __restrict__ a_dst,
                                                    unsigned short* __restrict__ wt2,
                                                    float* __restrict__ q_s,
                                                    float* __restrict__ q_d,
                                                    int* __restrict__ degs) {
    int bx = blockIdx.x;
    int tid = threadIdx.x;
    if (bx < 768) {
        int i = bx * 256 + tid;              // over 3*128*512
        if (i >= NLAYER * 128 * 512) return;
        int l = i >> 16;
        int rem = i & 65535;
        int jcol = rem >> 9;
        int p = rem & 511;
        int lanep = p >> 3, j8 = p & 7;
        int hp = j8 >> 1, bb = j8 & 1;
        int d = lanep * 2 + bb;
        wt2[i] = f2b(w_gat[(size_t)l * 65536 + (size_t)d * 512 + hp * 128 + jcol] * 0.25f);
    } else if (bx < 1152) {
        int bx2 = bx - 768;                  // over 3*128
        int l = bx2 >> 7, k = bx2 & 127;
        int hh_ = tid >> 6, lane = tid & 63;
        int d0 = lane * 2;
        size_t wb = (size_t)l * 65536 + (size_t)k * 512 + hh_ * 128;
        size_t ab = (size_t)l * 512 + hh_ * 128;
        float ps = w_gat[wb + d0] * a_src[ab + d0] + w_gat[wb + d0 + 1] * a_src[ab + d0 + 1];
        float pd = w_gat[wb + d0] * a_dst[ab + d0] + w_gat[wb + d0 + 1] * a_dst[ab + d0 + 1];
#pragma unroll
        for (int off = 32; off; off >>= 1) { ps += __shfl_xor(ps, off); pd += __shfl_xor(pd, off); }
        if (lane == 0) {
            q_s[(size_t)(l * 128 + k) * 4 + hh_] = ps;
            q_d[(size_t)(l * 128 + k) * 4 + hh_] = pd;
        }
    } else {
        int i0 = (bx - 1152) * 1024 + tid;
#pragma unroll
        for (int r = 0; r < 4; r++) {
            int i = i0 + r * 256;
            if (i < N_NODES) degs[i] = 0;
        }
    }
}

// ---------------------------------------------------------------------------
// prep_proj: fat projection (8 nodes/block) + layer-0 alpha.
// ---------------------------------------------------------------------------
__global__ __launch_bounds__(256) void prep_proj_kernel(const float* __restrict__ x,
                                                        const float* __restrict__ w,
                                                        const float* __restrict__ b,
                                                        unsigned short* __restrict__ h_bf,
                                                        const float* __restrict__ q_s,
                                                        const float* __restrict__ q_d,
                                                        float4* __restrict__ als4,
                                                        float4* __restrict__ ald4) {
    int bx = blockIdx.x;
    int tid = threadIdx.x;
    __shared__ float xr[8][F_NODE];
    __shared__ float vbuf[8][128];
    __shared__ float qs_t[512];
    __shared__ float qd_t[512];
    qs_t[tid] = q_s[tid]; qs_t[256 + tid] = q_s[256 + tid];
    qd_t[tid] = q_d[tid]; qd_t[256 + tid] = q_d[256 + tid];
    if (tid < 8 * F_NODE) {
        int nl = tid / F_NODE, k = tid % F_NODE;
        xr[nl][k] = x[(size_t)(bx * 8 + nl) * F_NODE + k];
    }
    __syncthreads();
    int d = tid & 127;
    int halfsel = tid >> 7;
#pragma unroll
    for (int p = 0; p < 4; p++) {
        int nl = p * 2 + halfsel;
        float acc = b[d];
#pragma unroll
        for (int k = 0; k < F_NODE; k++) acc += xr[nl][k] * w[k * DIM + d];
        float v = fmaxf(acc, 0.f);
        h_bf[(size_t)(bx * 8 + nl) * DIM + d] = f2b(v);
        vbuf[nl][d] = v;
    }
    __syncthreads();
    int wave = tid >> 6, lane = tid & 63;
#pragma unroll
    for (int t = 0; t < 2; t++) {
        int nl = wave * 2 + t;
        int n = bx * 8 + nl;
        float2 v2 = *(const float2*)&vbuf[nl][2 * lane];
        int k4 = 2 * lane * 4;
        float ps[4], pd[4];
#pragma unroll
        for (int hh_ = 0; hh_ < 4; hh_++) {
            ps[hh_] = v2.x * qs_t[k4 + hh_] + v2.y * qs_t[k4 + 4 + hh_];
            pd[hh_] = v2.x * qd_t[k4 + hh_] + v2.y * qd_t[k4 + 4 + hh_];
        }
#pragma unroll
        for (int off = 32; off; off >>= 1) {
#pragma unroll
            for (int hh_ = 0; hh_ < 4; hh_++) {
                ps[hh_] += __shfl_xor(ps[hh_], off);
                pd[hh_] += __shfl_xor(pd[hh_], off);
            }
        }
        if (lane == 0) {
            als4[n] = make_float4(ps[0], ps[1], ps[2], ps[3]);
            ald4[n] = make_float4(pd[0], pd[1], pd[2], pd[3]);
        }
    }
}

// ---------------------------------------------------------------------------
// prep_scat: fixed-capacity CSR scatter, 4 edges/thread. NOT idempotent.
// ---------------------------------------------------------------------------
__global__ __launch_bounds__(256) void prep_scat_kernel(const int* __restrict__ edge_index,
                                                        int* __restrict__ degs,
                                                        int* __restrict__ csr_src) {
    int base = blockIdx.x * 1024;
    int tid = threadIdx.x;
#pragma unroll
    for (int k = 0; k < 4; k++) {
        int e = base + k * 256 + tid;
        if (e < E_TOTAL) {
            int s, d;
            if (e < N_EDGES) { s = edge_index[e]; d = edge_index[N_EDGES + e]; }
            else             { s = e - N_EDGES;   d = s; }
            int pos = atomicAdd(&degs[d], 1);
            if (pos < CSR_CAP) csr_src[d * CSR_CAP + pos] = s;
        }
    }
}

// ---------------------------------------------------------------------------
// agg3 (R7): h-space aggregation, restructured from agg2 per R7 counters
// (VALUBusy 55% -> issue-bound; 16 readlane + exp + addressing dominated the
// per-edge path at ~15.5 VALU-inst/edge).
// Phase 1 (lane = edge): compute 4 exps from als4[src]+ald4[n], butterfly-
//   reduce sum(w) across wave, PRE-DIVIDE w' = w/sum, stash {w'4, byte-offset
//   src*256} in LDS. exp/readlane/divide leave the per-edge path.
// Phase 2 (per edge): uniform ds_read offset + uniform ds_read_b128 w'4
//   (broadcast, conflict-free) + 1 v_add + 1 global load + 4 pk_fma
//   ~ 8-9 inst/edge. Epilogue: pack+store only (already normalized).
// Math identical up to fp reordering (normalize-first); clamp-60 softmax
// unchanged (scale cancels in w/sum).
// REPS>1: diagnostic replay (bit-idempotent). No __syncthreads: each wave
// touches only its own LDS slice (wave-synchronous; compiler emits lgkmcnt).
// ---------------------------------------------------------------------------
template<int LYR, int REPS>
__global__ __launch_bounds__(256) void agg3_kernel(const unsigned short* __restrict__ h_bf,
                                                   const float4* __restrict__ als4,
                                                   const float4* __restrict__ ald4,
                                                   const int* __restrict__ degs,
                                                   const int* __restrict__ csr_src,
                                                   unsigned short* __restrict__ z) {
    __shared__ __align__(16) float wlds[4][CSR_CAP][4];
    __shared__ unsigned olds[4][CSR_CAP];
    int wave = threadIdx.x >> 6, lane = threadIdx.x & 63;
    int n = blockIdx.x * 4 + wave;
    if (n >= N_NODES) return;

    int deg = degs[n];
    deg = (deg < CSR_CAP) ? deg : CSR_CAP;
    const int* __restrict__ srcp = csr_src + (size_t)n * CSR_CAP;
    const unsigned char* __restrict__ hbase = (const unsigned char*)h_bf;
    float4 ad = ald4[n];
    unsigned lane4 = (unsigned)lane * 4u;

#pragma unroll 1
    for (int rep = 0; rep < REPS; ++rep) {
        // ---- phase 1: lane = edge ----
        float4 w4 = make_float4(0.f, 0.f, 0.f, 0.f);
        unsigned off_ = 0;
        if (lane < deg) {
            int s = srcp[lane];                       // coalesced
            off_ = (unsigned)s * 256u;                // byte offset into h_bf row
            float4 as = als4[s];                      // 16B gather, one per edge
            float v;
            v = as.x + ad.x; v = fmaxf(v, NEG_SLOPE * v); w4.x = __expf(fminf(v, 60.f));
            v = as.y + ad.y; v = fmaxf(v, NEG_SLOPE * v); w4.y = __expf(fminf(v, 60.f));
            v = as.z + ad.z; v = fmaxf(v, NEG_SLOPE * v); w4.z = __expf(fminf(v, 60.f));
            v = as.w + ad.w; v = fmaxf(v, NEG_SLOPE * v); w4.w = __expf(fminf(v, 60.f));
        }
        float lsx = w4.x, lsy = w4.y, lsz = w4.z, lsw = w4.w;
#pragma unroll
        for (int o = 32; o; o >>= 1) {
            lsx += __shfl_xor(lsx, o);
            lsy += __shfl_xor(lsy, o);
            lsz += __shfl_xor(lsz, o);
            lsw += __shfl_xor(lsw, o);
        }
        float ix = 1.f / lsx, iy = 1.f / lsy, iz = 1.f / lsz, iw = 1.f / lsw;
        if (lane < deg) {
            wlds[wave][lane][0] = w4.x * ix;
            wlds[wave][lane][1] = w4.y * iy;
            wlds[wave][lane][2] = w4.z * iz;
            wlds[wave][lane][3] = w4.w * iw;
            olds[wave][lane] = off_;
        }
        // ---- phase 2: gather-FMA ----
        f32x2 acc2[4] = {};
        int e = 0;
        for (; e + 4 <= deg; e += 4) {
            unsigned o0 = olds[wave][e];
            unsigned o1 = olds[wave][e + 1];
            unsigned o2 = olds[wave][e + 2];
            unsigned o3 = olds[wave][e + 3];
            unsigned hv0 = *(const unsigned*)(hbase + o0 + lane4);
            unsigned hv1 = *(const unsigned*)(hbase + o1 + lane4);
            unsigned hv2 = *(const unsigned*)(hbase + o2 + lane4);
            unsigned hv3 = *(const unsigned*)(hbase + o3 + lane4);
            float4 w0 = *(const float4*)&wlds[wave][e][0];
            float4 w1 = *(const float4*)&wlds[wave][e + 1][0];
            float4 w2 = *(const float4*)&wlds[wave][e + 2][0];
            float4 w3 = *(const float4*)&wlds[wave][e + 3][0];
            f32x2 f;
            f.x = blo(hv0); f.y = bhi(hv0);
            acc2[0] += w0.x * f; acc2[1] += w0.y * f; acc2[2] += w0.z * f; acc2[3] += w0.w * f;
            f.x = blo(hv1); f.y = bhi(hv1);
            acc2[0] += w1.x * f; acc2[1] += w1.y * f; acc2[2] += w1.z * f; acc2[3] += w1.w * f;
            f.x = blo(hv2); f.y = bhi(hv2);
            acc2[0] += w2.x * f; acc2[1] += w2.y * f; acc2[2] += w2.z * f; acc2[3] += w2.w * f;
            f.x = blo(hv3); f.y = bhi(hv3);
            acc2[0] += w3.x * f; acc2[1] += w3.y * f; acc2[2] += w3.z * f; acc2[3] += w3.w * f;
        }
        for (; e < deg; e++) {
            unsigned o0 = olds[wave][e];
            unsigned hv0 = *(const unsigned*)(hbase + o0 + lane4);
            float4 w0 = *(const float4*)&wlds[wave][e][0];
            f32x2 f;
            f.x = blo(hv0); f.y = bhi(hv0);
            acc2[0] += w0.x * f; acc2[1] += w0.y * f; acc2[2] += w0.z * f; acc2[3] += w0.w * f;
        }
        // ---- epilogue: pack & store (already normalized) ----
        uint4 pb;
        unsigned int* pc = &pb.x;
#pragma unroll
        for (int hh_ = 0; hh_ < 4; hh_++) {
            pc[hh_] = (unsigned)f2b(acc2[hh_].x) | ((unsigned)f2b(acc2[hh_].y) << 16);
        }
        *(uint4*)(z + (size_t)n * 512 + lane * 8) = pb;
    }
}

// ---------------------------------------------------------------------------
// zgemm v2: out = z[M,512] @ wt2[128,512]^T, fused bias + LN + ReLU + bf16
// residual + next-layer alpha. 512 thr / 8 waves; wave=(msub,nh) computes
// 16 rows x 64 cols. Verified R5: 18.8 -> 14.0 us/rep.
// ---------------------------------------------------------------------------
template<int LYR, int REPS>
__global__ __launch_bounds__(512) void zgemm_kernel(const unsigned short* __restrict__ z,
                                                    const unsigned short* __restrict__ wt2_l,
                                                    const float* __restrict__ b_gat,
                                                    const float* __restrict__ ln_w,
                                                    const float* __restrict__ ln_b,
                                                    const unsigned short* __restrict__ hb_in,
                                                    unsigned short* __restrict__ hb_out,
                                                    const float* __restrict__ q_s_next,
                                                    const float* __restrict__ q_d_next,
                                                    float4* __restrict__ als4,
                                                    float4* __restrict__ ald4,
                                                    int M) {
    __shared__ __align__(16) unsigned short As[64 * 136];
    __shared__ __align__(16) unsigned short Bs[128 * 136];
    __shared__ float redS[2][4][16];
    __shared__ float redQ[2][4][16];
    __shared__ float redPS[2][4][16][4];
    __shared__ float redPD[2][4][16][4];
    int tid = threadIdx.x;
    int m0 = blockIdx.x << 6;
    int wave = tid >> 6, lane = tid & 63;
    int lr = lane & 15, lg = lane >> 4;
    int msub = wave & 3, nh = wave >> 2;

    const uint4 zero4 = make_uint4(0, 0, 0, 0);
#pragma unroll 1
    for (int rep = 0; rep < REPS; ++rep) {
        if (REPS > 1) __syncthreads();
        f32x4 acc[4] = {};
        for (int kc = 0; kc < 4; kc++) {
#pragma unroll
            for (int p = 0; p < 2; p++) {        // A: 64 rows x 16 kg (512 thr)
                int i = p * 512 + tid;
                int row = i >> 4, kg = i & 15;
                int arow = m0 + row;
                uint4 av = (arow < M) ? *(const uint4*)(z + (size_t)arow * 512 + kc * 128 + kg * 8) : zero4;
                *(uint4*)&As[row * 136 + kg * 8] = av;
            }
#pragma unroll
            for (int p = 0; p < 4; p++) {        // B: 128 rows x 16 kg (512 thr)
                int i = p * 512 + tid;
                int row = i >> 4, kg = i & 15;
                uint4 bv = *(const uint4*)(wt2_l + (size_t)row * 512 + kc * 128 + kg * 8);
                *(uint4*)&Bs[row * 136 + kg * 8] = bv;
            }
            __syncthreads();
#pragma unroll
            for (int ks = 0; ks < 4; ks++) {
                bf16x8 af = *(const bf16x8*)&As[(msub * 16 + lr) * 136 + ks * 32 + lg * 8];
#pragma unroll
                for (int nt2 = 0; nt2 < 4; nt2++) {
                    int nt = nh * 4 + nt2;
                    bf16x8 bf_ = *(const bf16x8*)&Bs[(nt * 16 + lr) * 136 + ks * 32 + lg * 8];
                    acc[nt2] = __builtin_amdgcn_mfma_f32_16x16x32_bf16(af, bf_, acc[nt2], 0, 0, 0);
                }
            }
            __syncthreads();
        }

        // ---- epilogue: bias + LN (cross-half LDS reduce) + relu + residual ----
        float bg[4], lnw[4], lnb[4];
#pragma unroll
        for (int nt2 = 0; nt2 < 4; nt2++) {
            int col = nh * 64 + nt2 * 16 + lr;
            bg[nt2] = b_gat[col]; lnw[nt2] = ln_w[col]; lnb[nt2] = ln_b[col];
        }
        const bool do_alpha = (LYR + 1 < NLAYER);
        float4 qs4[4], qd4[4];
        if (do_alpha) {
#pragma unroll
            for (int nt2 = 0; nt2 < 4; nt2++) {
                int col = nh * 64 + nt2 * 16 + lr;
                qs4[nt2] = *(const float4*)(q_s_next + (size_t)col * 4);
                qd4[nt2] = *(const float4*)(q_d_next + (size_t)col * 4);
            }
        }
        float g[4][4];                       // [nt2][r]
#pragma unroll
        for (int nt2 = 0; nt2 < 4; nt2++)
#pragma unroll
            for (int r = 0; r < 4; r++) g[nt2][r] = acc[nt2][r] + bg[nt2];
#pragma unroll
        for (int r = 0; r < 4; r++) {
            float s = 0.f, q = 0.f;
#pragma unroll
            for (int nt2 = 0; nt2 < 4; nt2++) { s += g[nt2][r]; q += g[nt2][r] * g[nt2][r]; }
#pragma unroll
            for (int off = 1; off < 16; off <<= 1) { s += __shfl_xor(s, off); q += __shfl_xor(q, off); }
            if (lr == 0) { redS[nh][msub][lg * 4 + r] = s; redQ[nh][msub][lg * 4 + r] = q; }
        }
        __syncthreads();
        float o[4][4];
#pragma unroll
        for (int r = 0; r < 4; r++) {
            int row = m0 + msub * 16 + lg * 4 + r;
            bool valid = (row < M);
            int ri = lg * 4 + r;
            float mu = (redS[0][msub][ri] + redS[1][msub][ri]) * (1.f / 128.f);
            float qq = (redQ[0][msub][ri] + redQ[1][msub][ri]) * (1.f / 128.f);
            float rstd = rsqrtf(fmaxf(qq - mu * mu, 0.f) + LN_EPS);
#pragma unroll
            for (int nt2 = 0; nt2 < 4; nt2++) {
                int col = nh * 64 + nt2 * 16 + lr;
                float hv = valid ? b2f(hb_in[(size_t)row * 128 + col]) : 0.f;
                o[nt2][r] = fmaxf((g[nt2][r] - mu) * rstd * lnw[nt2] + lnb[nt2], 0.f) + hv;
                if (valid) hb_out[(size_t)row * 128 + col] = f2b(o[nt2][r]);
            }
        }
        if (do_alpha) {
            float ps[4][4] = {}, pd[4][4] = {};   // [r][h]
#pragma unroll
            for (int r = 0; r < 4; r++)
#pragma unroll
                for (int nt2 = 0; nt2 < 4; nt2++) {
                    ps[r][0] += o[nt2][r] * qs4[nt2].x; pd[r][0] += o[nt2][r] * qd4[nt2].x;
                    ps[r][1] += o[nt2][r] * qs4[nt2].y; pd[r][1] += o[nt2][r] * qd4[nt2].y;
                    ps[r][2] += o[nt2][r] * qs4[nt2].z; pd[r][2] += o[nt2][r] * qd4[nt2].z;
                    ps[r][3] += o[nt2][r] * qs4[nt2].w; pd[r][3] += o[nt2][r] * qd4[nt2].w;
                }
#pragma unroll
            for (int r = 0; r < 4; r++)
#pragma unroll
                for (int off = 1; off < 16; off <<= 1)
#pragma unroll
                    for (int hh_ = 0; hh_ < 4; hh_++) {
                        ps[r][hh_] += __shfl_xor(ps[r][hh_], off);
                        pd[r][hh_] += __shfl_xor(pd[r][hh_], off);
                    }
            if (lr == 0) {
#pragma unroll
                for (int r = 0; r < 4; r++)
#pragma unroll
                    for (int hh_ = 0; hh_ < 4; hh_++) {
                        redPS[nh][msub][lg * 4 + r][hh_] = ps[r][hh_];
                        redPD[nh][msub][lg * 4 + r][hh_] = pd[r][hh_];
                    }
            }
            __syncthreads();
            if (nh == 0 && lr == 0) {
#pragma unroll
                for (int r = 0; r < 4; r++) {
                    int row = m0 + msub * 16 + lg * 4 + r;
                    int ri = lg * 4 + r;
                    if (row < M) {
                        als4[row] = make_float4(redPS[0][msub][ri][0] + redPS[1][msub][ri][0],
                                                redPS[0][msub][ri][1] + redPS[1][msub][ri][1],
                                                redPS[0][msub][ri][2] + redPS[1][msub][ri][2],
                                                redPS[0][msub][ri][3] + redPS[1][msub][ri][3]);
                        ald4[row] = make_float4(redPD[0][msub][ri][0] + redPD[1][msub][ri][0],
                                                redPD[0][msub][ri][1] + redPD[1][msub][ri][1],
                                                redPD[0][msub][ri][2] + redPD[1][msub][ri][2],
                                                redPD[0][msub][ri][3] + redPD[1][msub][ri][3]);
                    }
                }
            }
        }
    }
}

// ---------------------------------------------------------------------------
// pool4: per-graph pooling split 4 ways — block (g,q4) computes partial
// sum/max over its quarter of graph g's nodes.
// ---------------------------------------------------------------------------
__device__ int lower_bound_dev(const int* a, int n, int v) {
    int lo = 0, hi = n;
    while (lo < hi) { int mid = (lo + hi) >> 1; if (a[mid] < v) lo = mid + 1; else hi = mid; }
    return lo;
}

__global__ __launch_bounds__(256) void pool4_kernel(const unsigned short* __restrict__ h,
                                                    const int* __restrict__ batch,
                                                    float* __restrict__ pool_ws) {
    int g = blockIdx.x >> 2, q4 = blockIdx.x & 3;
    int tid = threadIdx.x;
    __shared__ int bounds[2];
    __shared__ float psum[2][128];
    __shared__ float pmax[2][128];
    if (tid < 2) bounds[tid] = lower_bound_dev(batch, N_NODES, g + tid);
    __syncthreads();
    int lo = bounds[0], hi = bounds[1];
    int cnt = hi - lo;
    int per = (cnt + 3) >> 2;
    int beg = lo + q4 * per;
    int end = min(beg + per, hi);
    int rq = tid >> 7, d = tid & 127;
    float s = 0.f, m = -1e30f;
    for (int i = beg + rq; i < end; i += 2) {
        float v = b2f(h[(size_t)i * DIM + d]);
        s += v; m = fmaxf(m, v);
    }
    psum[rq][d] = s; pmax[rq][d] = m;
    __syncthreads();
    if (tid < 128) {
        float S = psum[0][d] + psum[1][d];
        float M = fmaxf(pmax[0][d], pmax[1][d]);
        pool_ws[(((size_t)g * 4 + q4) * 2 + 0) * 128 + d] = S;
        pool_ws[(((size_t)g * 4 + q4) * 2 + 1) * 128 + d] = M;
    }
}

// ---------------------------------------------------------------------------
// tail: per-graph MLP tail; pooling phase reads the 4 partials from pool_ws.
// ---------------------------------------------------------------------------
__global__ __launch_bounds__(512) void tail_kernel(
    const float* __restrict__ pool_ws, const int* __restrict__ batch,
    const float* __restrict__ tda,
    const float* __restrict__ w_t1, const float* __restrict__ b_t1,
    const float* __restrict__ w_t2, const float* __restrict__ b_t2,
    const float* __restrict__ w_sh1, const float* __restrict__ b_sh1,
    const float* __restrict__ w_sh2, const float* __restrict__ b_sh2,
    const float* __restrict__ w_h1, const float* __restrict__ b_h1,
    const float* __restrict__ w_h2, const float* __restrict__ b_h2,
    float* __restrict__ out) {
    __shared__ int bounds[2];
    __shared__ float comb[320];
    __shared__ float tr[F_TDA];
    __shared__ float t1[64];
    __shared__ float s1o[256];
    __shared__ float s2o[128];
    __shared__ float prods[NTASK * 64];
    int g = blockIdx.x, tid = threadIdx.x;

    if (tid < 2) bounds[tid] = lower_bound_dev(batch, N_NODES, g + tid);
    if (tid >= 2 && tid - 2 < F_TDA) tr[tid - 2] = tda[g * F_TDA + (tid - 2)];
    __syncthreads();
    int cnt = bounds[1] - bounds[0];
    if (tid < 128) {
        float S = 0.f, M = -1e30f;
#pragma unroll
        for (int q4 = 0; q4 < 4; q4++) {
            S += pool_ws[(((size_t)g * 4 + q4) * 2 + 0) * 128 + tid];
            M = fmaxf(M, pool_ws[(((size_t)g * 4 + q4) * 2 + 1) * 128 + tid]);
        }
        comb[tid] = S / fmaxf((float)cnt, 1.f);
        comb[128 + tid] = (cnt > 0) ? M : 0.f;
    } else if (tid >= 128 && tid < 192) {
        int j = tid - 128;
        float a = b_t1[j];
#pragma unroll
        for (int k = 0; k < F_TDA; k++) a += tr[k] * w_t1[k * 64 + j];
        t1[j] = fmaxf(a, 0.f);
    }
    __syncthreads();
    if (tid < 64) {
        float a = b_t2[tid];
#pragma unroll
        for (int k = 0; k < 64; k++) a += t1[k] * w_t2[k * 64 + tid];
        comb[256 + tid] = fmaxf(a, 0.f);
    }
    __syncthreads();
    if (tid < 256) {
        float a = b_sh1[tid];
        for (int k = 0; k < 320; k++) a += comb[k] * w_sh1[k * 256 + tid];
        s1o[tid] = fmaxf(a, 0.f);
    }
    __syncthreads();
    if (tid < 128) {
        float a = b_sh2[tid];
        for (int k = 0; k < 256; k++) a += s1o[k] * w_sh2[k * 128 + tid];
        s2o[tid] = fmaxf(a, 0.f);
    }
    __syncthreads();
    if (tid < NTASK * 64) {
        int t = tid >> 6, k = tid & 63;
        float a = b_h1[t * 64 + k];
#pragma unroll 16
        for (int dd = 0; dd < 128; dd++) a += s2o[dd] * w_h1[(size_t)t * 8192 + dd * 64 + k];
        prods[tid] = fmaxf(a, 0.f) * w_h2[t * 64 + k];
    }
    __syncthreads();
    if (tid < NTASK) {
        float p = b_h2[tid];
#pragma unroll 16
        for (int k = 0; k < 64; k++) p += prods[tid * 64 + k];
        out[tid * 256 + g] = p;
    }
}

// ---------------------------------------------------------------------------
extern "C" void kernel_launch(void* const* d_in, const int* in_sizes, int n_in,
                              void* d_out, int out_size, void* d_ws, size_t ws_size,
                              hipStream_t stream) {
    const float* x        = (const float*)d_in[0];
    const int*   edge_idx = (const int*)  d_in[1];
    const int*   batch    = (const int*)  d_in[2];
    const float* tda      = (const float*)d_in[3];
    const float* w_in     = (const float*)d_in[4];
    const float* b_in     = (const float*)d_in[5];
    const float* w_gat    = (const float*)d_in[6];
    const float* a_src    = (const float*)d_in[7];
    const float* a_dst    = (const float*)d_in[8];
    const float* b_gat    = (const float*)d_in[9];
    const float* ln_w     = (const float*)d_in[10];
    const float* ln_b     = (const float*)d_in[11];
    const float* w_tda1   = (const float*)d_in[12];
    const float* b_tda1   = (const float*)d_in[13];
    const float* w_tda2   = (const float*)d_in[14];
    const float* b_tda2   = (const float*)d_in[15];
    const float* w_sh1    = (const float*)d_in[16];
    const float* b_sh1    = (const float*)d_in[17];
    const float* w_sh2    = (const float*)d_in[18];
    const float* b_sh2    = (const float*)d_in[19];
    const float* w_h1     = (const float*)d_in[20];
    const float* b_h1     = (const float*)d_in[21];
    const float* w_h2     = (const float*)d_in[22];
    const float* b_h2     = (const float*)d_in[23];
    float* out = (float*)d_out;

    size_t off = 0;
    auto alloc = [&](size_t bytes) -> void* {
        void* p = (char*)d_ws + off;
        off += (bytes + 255) & ~(size_t)255;
        return p;
    };
    unsigned short* hb_a   = (unsigned short*)alloc((size_t)N_NODES * DIM * 2);
    unsigned short* hb_b   = (unsigned short*)alloc((size_t)N_NODES * DIM * 2);
    unsigned short* z      = (unsigned short*)alloc((size_t)N_NODES * 512 * 2);
    unsigned short* wt2    = (unsigned short*)alloc((size_t)NLAYER * 128 * 512 * 2);
    float*          q_s    = (float*)alloc((size_t)NLAYER * 128 * 4 * 4);
    float*          q_d    = (float*)alloc((size_t)NLAYER * 128 * 4 * 4);
    float4*         als4   = (float4*)alloc((size_t)N_NODES * 16);
    float4*         ald4   = (float4*)alloc((size_t)N_NODES * 16);
    int*            degs   = (int*)  alloc((size_t)N_NODES * 4);
    int*            csrsrc = (int*)  alloc((size_t)N_NODES * CSR_CAP * 4);
    float*          poolws = (float*)alloc((size_t)N_GRAPHS * 4 * 2 * 128 * 4);

    // qprep also zeroes degs (blocks 1152..1171) — no separate memset
    qprep_kernel<<<1172, 256, 0, stream>>>(w_gat, a_src, a_dst, wt2, q_s, q_d, degs);

    prep_proj_kernel<<<2500, 256, 0, stream>>>(x, w_in, b_in, hb_a, q_s, q_d, als4, ald4);
    int sb = (E_TOTAL + 1023) / 1024;   // 333
    prep_scat_kernel<<<sb, 256, 0, stream>>>(edge_idx, degs, csrsrc);

    int ab = (N_NODES + 3) / 4;
    int gb = (N_NODES + 63) / 64;
    // layer 0: hb_a -> hb_b
    agg3_kernel<0, 1><<<ab, 256, 0, stream>>>(hb_a, als4, ald4, degs, csrsrc, z);
    zgemm_kernel<0, 1><<<gb, 512, 0, stream>>>(z, wt2,
        b_gat, ln_w, ln_b, hb_a, hb_b, q_s + 512, q_d + 512, als4, ald4, N_NODES);
    // layer 1: hb_b -> hb_a
    agg3_kernel<1, 1><<<ab, 256, 0, stream>>>(hb_b, als4, ald4, degs, csrsrc, z);
    zgemm_kernel<1, 1><<<gb, 512, 0, stream>>>(z, wt2 + 65536,
        b_gat + DIM, ln_w + DIM, ln_b + DIM, hb_b, hb_a, q_s + 1024, q_d + 1024,
        als4, ald4, N_NODES);
    // layer 2: hb_a -> hb_b
    // DIAGNOSTIC (R7): agg3<2> replayed 12x — sole amplified kernel; read
    // T_agg3 = dur/12 + counters directly off the top dispatch.
    agg3_kernel<2, 12><<<ab, 256, 0, stream>>>(hb_a, als4, ald4, degs, csrsrc, z);
    zgemm_kernel<2, 1><<<gb, 512, 0, stream>>>(z, wt2 + 131072,
        b_gat + 2 * DIM, ln_w + 2 * DIM, ln_b + 2 * DIM, hb_a, hb_b,
        nullptr, nullptr, als4, ald4, N_NODES);

    pool4_kernel<<<N_GRAPHS * 4, 256, 0, stream>>>(hb_b, batch, poolws);
    tail_kernel<<<N_GRAPHS, 512, 0, stream>>>(
        poolws, batch, tda, w_tda1, b_tda1, w_tda2, b_tda2,
        w_sh1, b_sh1, w_sh2, b_sh2, w_h1, b_h1, w_h2, b_h2, out);
}

// Round 9
// 289.385 us; speedup vs baseline: 2.4867x; 1.3788x over previous
//
#include <hip/hip_runtime.h>
#include <hip/hip_bf16.h>
#include <cstdint>
#include <cstddef>

// Problem constants (match reference)
#define N_NODES  20000
#define N_EDGES  320000
#define E_TOTAL  (N_EDGES + N_NODES)   // with self loops = 340000
#define N_GRAPHS 256
#define F_NODE   11
#define F_TDA    30
#define DIM      128
#define NHEAD    4
#define NLAYER   3
#define NTASK    6
#define NEG_SLOPE 0.2f
#define LN_EPS   1e-5f
#define CSR_CAP  64   // fixed per-node capacity; deg ~ Poisson(17), P(>64) ~ 0

typedef short bf16x8 __attribute__((ext_vector_type(8)));
typedef float f32x4  __attribute__((ext_vector_type(4)));
typedef float f32x2  __attribute__((ext_vector_type(2)));

__device__ inline unsigned short f2b(float f) {
    unsigned int u = __builtin_bit_cast(unsigned int, f);
    u += 0x7fffu + ((u >> 16) & 1u);
    return (unsigned short)(u >> 16);
}
__device__ inline float blo(unsigned int u) { return __builtin_bit_cast(float, u << 16); }
__device__ inline float bhi(unsigned int u) { return __builtin_bit_cast(float, u & 0xffff0000u); }
__device__ inline float b2f(unsigned short b) {
    return __builtin_bit_cast(float, ((unsigned int)b) << 16);
}

// ---------------------------------------------------------------------------
// qprep: [0,768) Wstack cast (k-permuted, 0.25 folded); [768,1152) q vectors;
// [1152,1172) zero degs. Runs BEFORE prep so prep can read q_s/q_d safely.
// ---------------------------------------------------------------------------
__global__ __launch_bounds__(256) void qprep_kernel(const float* __restrict__ w_gat,
                                                    const float* __restrict__ a_src,
                                                    const float* __restrict__ a_dst,
                                                    unsigned short* __restrict__ wt2,
                                                    float* __restrict__ q_s,
                                                    float* __restrict__ q_d,
                                                    int* __restrict__ degs) {
    int bx = blockIdx.x;
    int tid = threadIdx.x;
    if (bx < 768) {
        int i = bx * 256 + tid;              // over 3*128*512
        if (i >= NLAYER * 128 * 512) return;
        int l = i >> 16;
        int rem = i & 65535;
        int jcol = rem >> 9;
        int p = rem & 511;
        int lanep = p >> 3, j8 = p & 7;
        int hp = j8 >> 1, bb = j8 & 1;
        int d = lanep * 2 + bb;
        wt2[i] = f2b(w_gat[(size_t)l * 65536 + (size_t)d * 512 + hp * 128 + jcol] * 0.25f);
    } else if (bx < 1152) {
        int bx2 = bx - 768;                  // over 3*128
        int l = bx2 >> 7, k = bx2 & 127;
        int hh_ = tid >> 6, lane = tid & 63;
        int d0 = lane * 2;
        size_t wb = (size_t)l * 65536 + (size_t)k * 512 + hh_ * 128;
        size_t ab = (size_t)l * 512 + hh_ * 128;
        float ps = w_gat[wb + d0] * a_src[ab + d0] + w_gat[wb + d0 + 1] * a_src[ab + d0 + 1];
        float pd = w_gat[wb + d0] * a_dst[ab + d0] + w_gat[wb + d0 + 1] * a_dst[ab + d0 + 1];
#pragma unroll
        for (int off = 32; off; off >>= 1) { ps += __shfl_xor(ps, off); pd += __shfl_xor(pd, off); }
        if (lane == 0) {
            q_s[(size_t)(l * 128 + k) * 4 + hh_] = ps;
            q_d[(size_t)(l * 128 + k) * 4 + hh_] = pd;
        }
    } else {
        int i0 = (bx - 1152) * 1024 + tid;
#pragma unroll
        for (int r = 0; r < 4; r++) {
            int i = i0 + r * 256;
            if (i < N_NODES) degs[i] = 0;
        }
    }
}

// ---------------------------------------------------------------------------
// prep_proj: fat projection (8 nodes/block) + layer-0 alpha.
// ---------------------------------------------------------------------------
__global__ __launch_bounds__(256) void prep_proj_kernel(const float* __restrict__ x,
                                                        const float* __restrict__ w,
                                                        const float* __restrict__ b,
                                                        unsigned short* __restrict__ h_bf,
                                                        const float* __restrict__ q_s,
                                                        const float* __restrict__ q_d,
                                                        float4* __restrict__ als4,
                                                        float4* __restrict__ ald4) {
    int bx = blockIdx.x;
    int tid = threadIdx.x;
    __shared__ float xr[8][F_NODE];
    __shared__ float vbuf[8][128];
    __shared__ float qs_t[512];
    __shared__ float qd_t[512];
    qs_t[tid] = q_s[tid]; qs_t[256 + tid] = q_s[256 + tid];
    qd_t[tid] = q_d[tid]; qd_t[256 + tid] = q_d[256 + tid];
    if (tid < 8 * F_NODE) {
        int nl = tid / F_NODE, k = tid % F_NODE;
        xr[nl][k] = x[(size_t)(bx * 8 + nl) * F_NODE + k];
    }
    __syncthreads();
    int d = tid & 127;
    int halfsel = tid >> 7;
#pragma unroll
    for (int p = 0; p < 4; p++) {
        int nl = p * 2 + halfsel;
        float acc = b[d];
#pragma unroll
        for (int k = 0; k < F_NODE; k++) acc += xr[nl][k] * w[k * DIM + d];
        float v = fmaxf(acc, 0.f);
        h_bf[(size_t)(bx * 8 + nl) * DIM + d] = f2b(v);
        vbuf[nl][d] = v;
    }
    __syncthreads();
    int wave = tid >> 6, lane = tid & 63;
#pragma unroll
    for (int t = 0; t < 2; t++) {
        int nl = wave * 2 + t;
        int n = bx * 8 + nl;
        float2 v2 = *(const float2*)&vbuf[nl][2 * lane];
        int k4 = 2 * lane * 4;
        float ps[4], pd[4];
#pragma unroll
        for (int hh_ = 0; hh_ < 4; hh_++) {
            ps[hh_] = v2.x * qs_t[k4 + hh_] + v2.y * qs_t[k4 + 4 + hh_];
            pd[hh_] = v2.x * qd_t[k4 + hh_] + v2.y * qd_t[k4 + 4 + hh_];
        }
#pragma unroll
        for (int off = 32; off; off >>= 1) {
#pragma unroll
            for (int hh_ = 0; hh_ < 4; hh_++) {
                ps[hh_] += __shfl_xor(ps[hh_], off);
                pd[hh_] += __shfl_xor(pd[hh_], off);
            }
        }
        if (lane == 0) {
            als4[n] = make_float4(ps[0], ps[1], ps[2], ps[3]);
            ald4[n] = make_float4(pd[0], pd[1], pd[2], pd[3]);
        }
    }
}

// ---------------------------------------------------------------------------
// prep_scat: fixed-capacity CSR scatter, 4 edges/thread. NOT idempotent.
// ---------------------------------------------------------------------------
__global__ __launch_bounds__(256) void prep_scat_kernel(const int* __restrict__ edge_index,
                                                        int* __restrict__ degs,
                                                        int* __restrict__ csr_src) {
    int base = blockIdx.x * 1024;
    int tid = threadIdx.x;
#pragma unroll
    for (int k = 0; k < 4; k++) {
        int e = base + k * 256 + tid;
        if (e < E_TOTAL) {
            int s, d;
            if (e < N_EDGES) { s = edge_index[e]; d = edge_index[N_EDGES + e]; }
            else             { s = e - N_EDGES;   d = s; }
            int pos = atomicAdd(&degs[d], 1);
            if (pos < CSR_CAP) csr_src[d * CSR_CAP + pos] = s;
        }
    }
}

// ---------------------------------------------------------------------------
// agg3 (R7, verified R8: 21.6 -> 13.2 us; VALUBusy 81%, Occ 67%, VGPR 32).
// Phase 1 (lane = edge): 4 exps from als4[src]+ald4[n], butterfly-reduce sum,
//   PRE-DIVIDE w' = w/sum, stash {w'4, byte-offset src*256} in LDS.
// Phase 2 (per edge): uniform ds_read offset + uniform ds_read_b128 w'4 +
//   1 v_add + 1 global load + 4 pk_fma. Epilogue: pack+store only.
// Remaining ceiling is the VALU issue rate (~8 inst/edge, 4 of them pk_fma).
// ---------------------------------------------------------------------------
template<int LYR, int REPS>
__global__ __launch_bounds__(256) void agg3_kernel(const unsigned short* __restrict__ h_bf,
                                                   const float4* __restrict__ als4,
                                                   const float4* __restrict__ ald4,
                                                   const int* __restrict__ degs,
                                                   const int* __restrict__ csr_src,
                                                   unsigned short* __restrict__ z) {
    __shared__ __align__(16) float wlds[4][CSR_CAP][4];
    __shared__ unsigned olds[4][CSR_CAP];
    int wave = threadIdx.x >> 6, lane = threadIdx.x & 63;
    int n = blockIdx.x * 4 + wave;
    if (n >= N_NODES) return;

    int deg = degs[n];
    deg = (deg < CSR_CAP) ? deg : CSR_CAP;
    const int* __restrict__ srcp = csr_src + (size_t)n * CSR_CAP;
    const unsigned char* __restrict__ hbase = (const unsigned char*)h_bf;
    float4 ad = ald4[n];
    unsigned lane4 = (unsigned)lane * 4u;

#pragma unroll 1
    for (int rep = 0; rep < REPS; ++rep) {
        // ---- phase 1: lane = edge ----
        float4 w4 = make_float4(0.f, 0.f, 0.f, 0.f);
        unsigned off_ = 0;
        if (lane < deg) {
            int s = srcp[lane];                       // coalesced
            off_ = (unsigned)s * 256u;                // byte offset into h_bf row
            float4 as = als4[s];                      // 16B gather, one per edge
            float v;
            v = as.x + ad.x; v = fmaxf(v, NEG_SLOPE * v); w4.x = __expf(fminf(v, 60.f));
            v = as.y + ad.y; v = fmaxf(v, NEG_SLOPE * v); w4.y = __expf(fminf(v, 60.f));
            v = as.z + ad.z; v = fmaxf(v, NEG_SLOPE * v); w4.z = __expf(fminf(v, 60.f));
            v = as.w + ad.w; v = fmaxf(v, NEG_SLOPE * v); w4.w = __expf(fminf(v, 60.f));
        }
        float lsx = w4.x, lsy = w4.y, lsz = w4.z, lsw = w4.w;
#pragma unroll
        for (int o = 32; o; o >>= 1) {
            lsx += __shfl_xor(lsx, o);
            lsy += __shfl_xor(lsy, o);
            lsz += __shfl_xor(lsz, o);
            lsw += __shfl_xor(lsw, o);
        }
        float ix = 1.f / lsx, iy = 1.f / lsy, iz = 1.f / lsz, iw = 1.f / lsw;
        if (lane < deg) {
            wlds[wave][lane][0] = w4.x * ix;
            wlds[wave][lane][1] = w4.y * iy;
            wlds[wave][lane][2] = w4.z * iz;
            wlds[wave][lane][3] = w4.w * iw;
            olds[wave][lane] = off_;
        }
        // ---- phase 2: gather-FMA ----
        f32x2 acc2[4] = {};
        int e = 0;
        for (; e + 4 <= deg; e += 4) {
            unsigned o0 = olds[wave][e];
            unsigned o1 = olds[wave][e + 1];
            unsigned o2 = olds[wave][e + 2];
            unsigned o3 = olds[wave][e + 3];
            unsigned hv0 = *(const unsigned*)(hbase + o0 + lane4);
            unsigned hv1 = *(const unsigned*)(hbase + o1 + lane4);
            unsigned hv2 = *(const unsigned*)(hbase + o2 + lane4);
            unsigned hv3 = *(const unsigned*)(hbase + o3 + lane4);
            float4 w0 = *(const float4*)&wlds[wave][e][0];
            float4 w1 = *(const float4*)&wlds[wave][e + 1][0];
            float4 w2 = *(const float4*)&wlds[wave][e + 2][0];
            float4 w3 = *(const float4*)&wlds[wave][e + 3][0];
            f32x2 f;
            f.x = blo(hv0); f.y = bhi(hv0);
            acc2[0] += w0.x * f; acc2[1] += w0.y * f; acc2[2] += w0.z * f; acc2[3] += w0.w * f;
            f.x = blo(hv1); f.y = bhi(hv1);
            acc2[0] += w1.x * f; acc2[1] += w1.y * f; acc2[2] += w1.z * f; acc2[3] += w1.w * f;
            f.x = blo(hv2); f.y = bhi(hv2);
            acc2[0] += w2.x * f; acc2[1] += w2.y * f; acc2[2] += w2.z * f; acc2[3] += w2.w * f;
            f.x = blo(hv3); f.y = bhi(hv3);
            acc2[0] += w3.x * f; acc2[1] += w3.y * f; acc2[2] += w3.z * f; acc2[3] += w3.w * f;
        }
        for (; e < deg; e++) {
            unsigned o0 = olds[wave][e];
            unsigned hv0 = *(const unsigned*)(hbase + o0 + lane4);
            float4 w0 = *(const float4*)&wlds[wave][e][0];
            f32x2 f;
            f.x = blo(hv0); f.y = bhi(hv0);
            acc2[0] += w0.x * f; acc2[1] += w0.y * f; acc2[2] += w0.z * f; acc2[3] += w0.w * f;
        }
        // ---- epilogue: pack & store (already normalized) ----
        uint4 pb;
        unsigned int* pc = &pb.x;
#pragma unroll
        for (int hh_ = 0; hh_ < 4; hh_++) {
            pc[hh_] = (unsigned)f2b(acc2[hh_].x) | ((unsigned)f2b(acc2[hh_].y) << 16);
        }
        *(uint4*)(z + (size_t)n * 512 + lane * 8) = pb;
    }
}

// ---------------------------------------------------------------------------
// zgemm v3 (R8): out = z[M,512] @ wt2[128,512]^T, fused bias + LN + ReLU +
// bf16 residual + next-layer alpha.
// R8 change: BM 64 -> 32. Grid 313 -> 625 blocks (20000/32 exact) — R5
// counters still showed Occupancy 14% / MfmaUtil 7% at 313 blocks (1.2/CU):
// the kernel is CU-coverage-starved. LDS 53 -> 49 KB (3 blocks/CU).
// Wave layout 2x4: msub=wave&1 (16 rows), nh=wave>>1 (32 cols, 2 MFMA tiles).
// LN/alpha stats reduce across the 4 N-quarters via LDS (sum/sumsq form).
// ---------------------------------------------------------------------------
template<int LYR>
__global__ __launch_bounds__(512) void zgemm_kernel(const unsigned short* __restrict__ z,
                                                    const unsigned short* __restrict__ wt2_l,
                                                    const float* __restrict__ b_gat,
                                                    const float* __restrict__ ln_w,
                                                    const float* __restrict__ ln_b,
                                                    const unsigned short* __restrict__ hb_in,
                                                    unsigned short* __restrict__ hb_out,
                                                    const float* __restrict__ q_s_next,
                                                    const float* __restrict__ q_d_next,
                                                    float4* __restrict__ als4,
                                                    float4* __restrict__ ald4,
                                                    int M) {
    __shared__ __align__(16) unsigned short As[32 * 136];
    __shared__ __align__(16) unsigned short Bs[128 * 136];
    __shared__ float redS[4][2][16];
    __shared__ float redQ[4][2][16];
    __shared__ float redPS[4][2][16][4];
    __shared__ float redPD[4][2][16][4];
    int tid = threadIdx.x;
    int m0 = blockIdx.x << 5;
    int wave = tid >> 6, lane = tid & 63;
    int lr = lane & 15, lg = lane >> 4;
    int msub = wave & 1, nh = wave >> 1;

    const uint4 zero4 = make_uint4(0, 0, 0, 0);
    f32x4 acc[2] = {};
    for (int kc = 0; kc < 4; kc++) {
        {                                    // A: 32 rows x 16 kg (512 thr, 1 each)
            int row = tid >> 4, kg = tid & 15;
            int arow = m0 + row;
            uint4 av = (arow < M) ? *(const uint4*)(z + (size_t)arow * 512 + kc * 128 + kg * 8) : zero4;
            *(uint4*)&As[row * 136 + kg * 8] = av;
        }
#pragma unroll
        for (int p = 0; p < 4; p++) {        // B: 128 rows x 16 kg (512 thr)
            int i = p * 512 + tid;
            int row = i >> 4, kg = i & 15;
            uint4 bv = *(const uint4*)(wt2_l + (size_t)row * 512 + kc * 128 + kg * 8);
            *(uint4*)&Bs[row * 136 + kg * 8] = bv;
        }
        __syncthreads();
#pragma unroll
        for (int ks = 0; ks < 4; ks++) {
            bf16x8 af = *(const bf16x8*)&As[(msub * 16 + lr) * 136 + ks * 32 + lg * 8];
#pragma unroll
            for (int nt2 = 0; nt2 < 2; nt2++) {
                int nt = nh * 2 + nt2;
                bf16x8 bf_ = *(const bf16x8*)&Bs[(nt * 16 + lr) * 136 + ks * 32 + lg * 8];
                acc[nt2] = __builtin_amdgcn_mfma_f32_16x16x32_bf16(af, bf_, acc[nt2], 0, 0, 0);
            }
        }
        __syncthreads();
    }

    // ---- epilogue: bias + LN (cross-quarter LDS reduce) + relu + residual ----
    float bg[2], lnw[2], lnb[2];
#pragma unroll
    for (int nt2 = 0; nt2 < 2; nt2++) {
        int col = nh * 32 + nt2 * 16 + lr;
        bg[nt2] = b_gat[col]; lnw[nt2] = ln_w[col]; lnb[nt2] = ln_b[col];
    }
    const bool do_alpha = (LYR + 1 < NLAYER);
    float4 qs4[2], qd4[2];
    if (do_alpha) {
#pragma unroll
        for (int nt2 = 0; nt2 < 2; nt2++) {
            int col = nh * 32 + nt2 * 16 + lr;
            qs4[nt2] = *(const float4*)(q_s_next + (size_t)col * 4);
            qd4[nt2] = *(const float4*)(q_d_next + (size_t)col * 4);
        }
    }
    float g[2][4];                       // [nt2][r]
#pragma unroll
    for (int nt2 = 0; nt2 < 2; nt2++)
#pragma unroll
        for (int r = 0; r < 4; r++) g[nt2][r] = acc[nt2][r] + bg[nt2];
#pragma unroll
    for (int r = 0; r < 4; r++) {
        float s = 0.f, q = 0.f;
#pragma unroll
        for (int nt2 = 0; nt2 < 2; nt2++) { s += g[nt2][r]; q += g[nt2][r] * g[nt2][r]; }
#pragma unroll
        for (int off = 1; off < 16; off <<= 1) { s += __shfl_xor(s, off); q += __shfl_xor(q, off); }
        if (lr == 0) { redS[nh][msub][lg * 4 + r] = s; redQ[nh][msub][lg * 4 + r] = q; }
    }
    __syncthreads();
    float o[2][4];
#pragma unroll
    for (int r = 0; r < 4; r++) {
        int row = m0 + msub * 16 + lg * 4 + r;
        bool valid = (row < M);
        int ri = lg * 4 + r;
        float su = redS[0][msub][ri] + redS[1][msub][ri] + redS[2][msub][ri] + redS[3][msub][ri];
        float qu = redQ[0][msub][ri] + redQ[1][msub][ri] + redQ[2][msub][ri] + redQ[3][msub][ri];
        float mu = su * (1.f / 128.f);
        float qq = qu * (1.f / 128.f);
        float rstd = rsqrtf(fmaxf(qq - mu * mu, 0.f) + LN_EPS);
#pragma unroll
        for (int nt2 = 0; nt2 < 2; nt2++) {
            int col = nh * 32 + nt2 * 16 + lr;
            float hv = valid ? b2f(hb_in[(size_t)row * 128 + col]) : 0.f;
            o[nt2][r] = fmaxf((g[nt2][r] - mu) * rstd * lnw[nt2] + lnb[nt2], 0.f) + hv;
            if (valid) hb_out[(size_t)row * 128 + col] = f2b(o[nt2][r]);
        }
    }
    if (do_alpha) {
        float ps[4][4] = {}, pd[4][4] = {};   // [r][h]
#pragma unroll
        for (int r = 0; r < 4; r++)
#pragma unroll
            for (int nt2 = 0; nt2 < 2; nt2++) {
                ps[r][0] += o[nt2][r] * qs4[nt2].x; pd[r][0] += o[nt2][r] * qd4[nt2].x;
                ps[r][1] += o[nt2][r] * qs4[nt2].y; pd[r][1] += o[nt2][r] * qd4[nt2].y;
                ps[r][2] += o[nt2][r] * qs4[nt2].z; pd[r][2] += o[nt2][r] * qd4[nt2].z;
                ps[r][3] += o[nt2][r] * qs4[nt2].w; pd[r][3] += o[nt2][r] * qd4[nt2].w;
            }
#pragma unroll
        for (int r = 0; r < 4; r++)
#pragma unroll
            for (int off = 1; off < 16; off <<= 1)
#pragma unroll
                for (int hh_ = 0; hh_ < 4; hh_++) {
                    ps[r][hh_] += __shfl_xor(ps[r][hh_], off);
                    pd[r][hh_] += __shfl_xor(pd[r][hh_], off);
                }
        if (lr == 0) {
#pragma unroll
            for (int r = 0; r < 4; r++)
#pragma unroll
                for (int hh_ = 0; hh_ < 4; hh_++) {
                    redPS[nh][msub][lg * 4 + r][hh_] = ps[r][hh_];
                    redPD[nh][msub][lg * 4 + r][hh_] = pd[r][hh_];
                }
        }
        __syncthreads();
        if (nh == 0 && lr == 0) {
#pragma unroll
            for (int r = 0; r < 4; r++) {
                int row = m0 + msub * 16 + lg * 4 + r;
                int ri = lg * 4 + r;
                if (row < M) {
                    float4 a0, a1;
#pragma unroll
                    for (int hh_ = 0; hh_ < 4; hh_++) {
                        (&a0.x)[hh_] = redPS[0][msub][ri][hh_] + redPS[1][msub][ri][hh_]
                                     + redPS[2][msub][ri][hh_] + redPS[3][msub][ri][hh_];
                        (&a1.x)[hh_] = redPD[0][msub][ri][hh_] + redPD[1][msub][ri][hh_]
                                     + redPD[2][msub][ri][hh_] + redPD[3][msub][ri][hh_];
                    }
                    als4[row] = a0;
                    ald4[row] = a1;
                }
            }
        }
    }
}

// ---------------------------------------------------------------------------
// pool4: per-graph pooling split 4 ways — block (g,q4) computes partial
// sum/max over its quarter of graph g's nodes.
// ---------------------------------------------------------------------------
__device__ int lower_bound_dev(const int* a, int n, int v) {
    int lo = 0, hi = n;
    while (lo < hi) { int mid = (lo + hi) >> 1; if (a[mid] < v) lo = mid + 1; else hi = mid; }
    return lo;
}

__global__ __launch_bounds__(256) void pool4_kernel(const unsigned short* __restrict__ h,
                                                    const int* __restrict__ batch,
                                                    float* __restrict__ pool_ws) {
    int g = blockIdx.x >> 2, q4 = blockIdx.x & 3;
    int tid = threadIdx.x;
    __shared__ int bounds[2];
    __shared__ float psum[2][128];
    __shared__ float pmax[2][128];
    if (tid < 2) bounds[tid] = lower_bound_dev(batch, N_NODES, g + tid);
    __syncthreads();
    int lo = bounds[0], hi = bounds[1];
    int cnt = hi - lo;
    int per = (cnt + 3) >> 2;
    int beg = lo + q4 * per;
    int end = min(beg + per, hi);
    int rq = tid >> 7, d = tid & 127;
    float s = 0.f, m = -1e30f;
    for (int i = beg + rq; i < end; i += 2) {
        float v = b2f(h[(size_t)i * DIM + d]);
        s += v; m = fmaxf(m, v);
    }
    psum[rq][d] = s; pmax[rq][d] = m;
    __syncthreads();
    if (tid < 128) {
        float S = psum[0][d] + psum[1][d];
        float M = fmaxf(pmax[0][d], pmax[1][d]);
        pool_ws[(((size_t)g * 4 + q4) * 2 + 0) * 128 + d] = S;
        pool_ws[(((size_t)g * 4 + q4) * 2 + 1) * 128 + d] = M;
    }
}

// ---------------------------------------------------------------------------
// tail: per-graph MLP tail; pooling phase reads the 4 partials from pool_ws.
// ---------------------------------------------------------------------------
__global__ __launch_bounds__(512) void tail_kernel(
    const float* __restrict__ pool_ws, const int* __restrict__ batch,
    const float* __restrict__ tda,
    const float* __restrict__ w_t1, const float* __restrict__ b_t1,
    const float* __restrict__ w_t2, const float* __restrict__ b_t2,
    const float* __restrict__ w_sh1, const float* __restrict__ b_sh1,
    const float* __restrict__ w_sh2, const float* __restrict__ b_sh2,
    const float* __restrict__ w_h1, const float* __restrict__ b_h1,
    const float* __restrict__ w_h2, const float* __restrict__ b_h2,
    float* __restrict__ out) {
    __shared__ int bounds[2];
    __shared__ float comb[320];
    __shared__ float tr[F_TDA];
    __shared__ float t1[64];
    __shared__ float s1o[256];
    __shared__ float s2o[128];
    __shared__ float prods[NTASK * 64];
    int g = blockIdx.x, tid = threadIdx.x;

    if (tid < 2) bounds[tid] = lower_bound_dev(batch, N_NODES, g + tid);
    if (tid >= 2 && tid - 2 < F_TDA) tr[tid - 2] = tda[g * F_TDA + (tid - 2)];
    __syncthreads();
    int cnt = bounds[1] - bounds[0];
    if (tid < 128) {
        float S = 0.f, M = -1e30f;
#pragma unroll
        for (int q4 = 0; q4 < 4; q4++) {
            S += pool_ws[(((size_t)g * 4 + q4) * 2 + 0) * 128 + tid];
            M = fmaxf(M, pool_ws[(((size_t)g * 4 + q4) * 2 + 1) * 128 + tid]);
        }
        comb[tid] = S / fmaxf((float)cnt, 1.f);
        comb[128 + tid] = (cnt > 0) ? M : 0.f;
    } else if (tid >= 128 && tid < 192) {
        int j = tid - 128;
        float a = b_t1[j];
#pragma unroll
        for (int k = 0; k < F_TDA; k++) a += tr[k] * w_t1[k * 64 + j];
        t1[j] = fmaxf(a, 0.f);
    }
    __syncthreads();
    if (tid < 64) {
        float a = b_t2[tid];
#pragma unroll
        for (int k = 0; k < 64; k++) a += t1[k] * w_t2[k * 64 + tid];
        comb[256 + tid] = fmaxf(a, 0.f);
    }
    __syncthreads();
    if (tid < 256) {
        float a = b_sh1[tid];
        for (int k = 0; k < 320; k++) a += comb[k] * w_sh1[k * 256 + tid];
        s1o[tid] = fmaxf(a, 0.f);
    }
    __syncthreads();
    if (tid < 128) {
        float a = b_sh2[tid];
        for (int k = 0; k < 256; k++) a += s1o[k] * w_sh2[k * 128 + tid];
        s2o[tid] = fmaxf(a, 0.f);
    }
    __syncthreads();
    if (tid < NTASK * 64) {
        int t = tid >> 6, k = tid & 63;
        float a = b_h1[t * 64 + k];
#pragma unroll 16
        for (int dd = 0; dd < 128; dd++) a += s2o[dd] * w_h1[(size_t)t * 8192 + dd * 64 + k];
        prods[tid] = fmaxf(a, 0.f) * w_h2[t * 64 + k];
    }
    __syncthreads();
    if (tid < NTASK) {
        float p = b_h2[tid];
#pragma unroll 16
        for (int k = 0; k < 64; k++) p += prods[tid * 64 + k];
        out[tid * 256 + g] = p;
    }
}

// ---------------------------------------------------------------------------
extern "C" void kernel_launch(void* const* d_in, const int* in_sizes, int n_in,
                              void* d_out, int out_size, void* d_ws, size_t ws_size,
                              hipStream_t stream) {
    const float* x        = (const float*)d_in[0];
    const int*   edge_idx = (const int*)  d_in[1];
    const int*   batch    = (const int*)  d_in[2];
    const float* tda      = (const float*)d_in[3];
    const float* w_in     = (const float*)d_in[4];
    const float* b_in     = (const float*)d_in[5];
    const float* w_gat    = (const float*)d_in[6];
    const float* a_src    = (const float*)d_in[7];
    const float* a_dst    = (const float*)d_in[8];
    const float* b_gat    = (const float*)d_in[9];
    const float* ln_w     = (const float*)d_in[10];
    const float* ln_b     = (const float*)d_in[11];
    const float* w_tda1   = (const float*)d_in[12];
    const float* b_tda1   = (const float*)d_in[13];
    const float* w_tda2   = (const float*)d_in[14];
    const float* b_tda2   = (const float*)d_in[15];
    const float* w_sh1    = (const float*)d_in[16];
    const float* b_sh1    = (const float*)d_in[17];
    const float* w_sh2    = (const float*)d_in[18];
    const float* b_sh2    = (const float*)d_in[19];
    const float* w_h1     = (const float*)d_in[20];
    const float* b_h1     = (const float*)d_in[21];
    const float* w_h2     = (const float*)d_in[22];
    const float* b_h2     = (const float*)d_in[23];
    float* out = (float*)d_out;

    size_t off = 0;
    auto alloc = [&](size_t bytes) -> void* {
        void* p = (char*)d_ws + off;
        off += (bytes + 255) & ~(size_t)255;
        return p;
    };
    unsigned short* hb_a   = (unsigned short*)alloc((size_t)N_NODES * DIM * 2);
    unsigned short* hb_b   = (unsigned short*)alloc((size_t)N_NODES * DIM * 2);
    unsigned short* z      = (unsigned short*)alloc((size_t)N_NODES * 512 * 2);
    unsigned short* wt2    = (unsigned short*)alloc((size_t)NLAYER * 128 * 512 * 2);
    float*          q_s    = (float*)alloc((size_t)NLAYER * 128 * 4 * 4);
    float*          q_d    = (float*)alloc((size_t)NLAYER * 128 * 4 * 4);
    float4*         als4   = (float4*)alloc((size_t)N_NODES * 16);
    float4*         ald4   = (float4*)alloc((size_t)N_NODES * 16);
    int*            degs   = (int*)  alloc((size_t)N_NODES * 4);
    int*            csrsrc = (int*)  alloc((size_t)N_NODES * CSR_CAP * 4);
    float*          poolws = (float*)alloc((size_t)N_GRAPHS * 4 * 2 * 128 * 4);

    // qprep also zeroes degs (blocks 1152..1171) — no separate memset
    qprep_kernel<<<1172, 256, 0, stream>>>(w_gat, a_src, a_dst, wt2, q_s, q_d, degs);

    prep_proj_kernel<<<2500, 256, 0, stream>>>(x, w_in, b_in, hb_a, q_s, q_d, als4, ald4);
    int sb = (E_TOTAL + 1023) / 1024;   // 333
    prep_scat_kernel<<<sb, 256, 0, stream>>>(edge_idx, degs, csrsrc);

    int ab = (N_NODES + 3) / 4;
    int gb = (N_NODES + 31) / 32;        // 625 blocks (BM=32, exact)
    // layer 0: hb_a -> hb_b
    agg3_kernel<0, 1><<<ab, 256, 0, stream>>>(hb_a, als4, ald4, degs, csrsrc, z);
    zgemm_kernel<0><<<gb, 512, 0, stream>>>(z, wt2,
        b_gat, ln_w, ln_b, hb_a, hb_b, q_s + 512, q_d + 512, als4, ald4, N_NODES);
    // layer 1: hb_b -> hb_a
    agg3_kernel<1, 1><<<ab, 256, 0, stream>>>(hb_b, als4, ald4, degs, csrsrc, z);
    zgemm_kernel<1><<<gb, 512, 0, stream>>>(z, wt2 + 65536,
        b_gat + DIM, ln_w + DIM, ln_b + DIM, hb_b, hb_a, q_s + 1024, q_d + 1024,
        als4, ald4, N_NODES);
    // layer 2: hb_a -> hb_b
    agg3_kernel<2, 1><<<ab, 256, 0, stream>>>(hb_a, als4, ald4, degs, csrsrc, z);
    zgemm_kernel<2><<<gb, 512, 0, stream>>>(z, wt2 + 131072,
        b_gat + 2 * DIM, ln_w + 2 * DIM, ln_b + 2 * DIM, hb_a, hb_b,
        nullptr, nullptr, als4, ald4, N_NODES);

    pool4_kernel<<<N_GRAPHS * 4, 256, 0, stream>>>(hb_b, batch, poolws);
    tail_kernel<<<N_GRAPHS, 512, 0, stream>>>(
        poolws, batch, tda, w_tda1, b_tda1, w_tda2, b_tda2,
        w_sh1, b_sh1, w_sh2, b_sh2, w_h1, b_h1, w_h2, b_h2, out);
}

// Round 10
// 280.836 us; speedup vs baseline: 2.5624x; 1.0304x over previous
//
#include <hip/hip_runtime.h>
#include <hip/hip_bf16.h>
#include <cstdint>
#include <cstddef>

// Problem constants (match reference)
#define N_NODES  20000
#define N_EDGES  320000
#define E_TOTAL  (N_EDGES + N_NODES)   // with self loops = 340000
#define N_GRAPHS 256
#define F_NODE   11
#define F_TDA    30
#define DIM      128
#define NHEAD    4
#define NLAYER   3
#define NTASK    6
#define NEG_SLOPE 0.2f
#define LN_EPS   1e-5f
#define CSR_CAP  64   // fixed per-node capacity; deg ~ Poisson(17), P(>64) ~ 0

typedef short bf16x8 __attribute__((ext_vector_type(8)));
typedef float f32x4  __attribute__((ext_vector_type(4)));
typedef float f32x2  __attribute__((ext_vector_type(2)));

__device__ inline unsigned short f2b(float f) {
    unsigned int u = __builtin_bit_cast(unsigned int, f);
    u += 0x7fffu + ((u >> 16) & 1u);
    return (unsigned short)(u >> 16);
}
__device__ inline float blo(unsigned int u) { return __builtin_bit_cast(float, u << 16); }
__device__ inline float bhi(unsigned int u) { return __builtin_bit_cast(float, u & 0xffff0000u); }
__device__ inline float b2f(unsigned short b) {
    return __builtin_bit_cast(float, ((unsigned int)b) << 16);
}

// ---------------------------------------------------------------------------
// qprep: [0,768) Wstack cast (k-permuted, 0.25 folded); [768,1152) q vectors;
// [1152,1172) zero degs. Runs BEFORE prep so prep can read q_s/q_d safely.
// ---------------------------------------------------------------------------
__global__ __launch_bounds__(256) void qprep_kernel(const float* __restrict__ w_gat,
                                                    const float* __restrict__ a_src,
                                                    const float* __restrict__ a_dst,
                                                    unsigned short* __restrict__ wt2,
                                                    float* __restrict__ q_s,
                                                    float* __restrict__ q_d,
                                                    int* __restrict__ degs) {
    int bx = blockIdx.x;
    int tid = threadIdx.x;
    if (bx < 768) {
        int i = bx * 256 + tid;              // over 3*128*512
        if (i >= NLAYER * 128 * 512) return;
        int l = i >> 16;
        int rem = i & 65535;
        int jcol = rem >> 9;
        int p = rem & 511;
        int lanep = p >> 3, j8 = p & 7;
        int hp = j8 >> 1, bb = j8 & 1;
        int d = lanep * 2 + bb;
        wt2[i] = f2b(w_gat[(size_t)l * 65536 + (size_t)d * 512 + hp * 128 + jcol] * 0.25f);
    } else if (bx < 1152) {
        int bx2 = bx - 768;                  // over 3*128
        int l = bx2 >> 7, k = bx2 & 127;
        int hh_ = tid >> 6, lane = tid & 63;
        int d0 = lane * 2;
        size_t wb = (size_t)l * 65536 + (size_t)k * 512 + hh_ * 128;
        size_t ab = (size_t)l * 512 + hh_ * 128;
        float ps = w_gat[wb + d0] * a_src[ab + d0] + w_gat[wb + d0 + 1] * a_src[ab + d0 + 1];
        float pd = w_gat[wb + d0] * a_dst[ab + d0] + w_gat[wb + d0 + 1] * a_dst[ab + d0 + 1];
#pragma unroll
        for (int off = 32; off; off >>= 1) { ps += __shfl_xor(ps, off); pd += __shfl_xor(pd, off); }
        if (lane == 0) {
            q_s[(size_t)(l * 128 + k) * 4 + hh_] = ps;
            q_d[(size_t)(l * 128 + k) * 4 + hh_] = pd;
        }
    } else {
        int i0 = (bx - 1152) * 1024 + tid;
#pragma unroll
        for (int r = 0; r < 4; r++) {
            int i = i0 + r * 256;
            if (i < N_NODES) degs[i] = 0;
        }
    }
}

// ---------------------------------------------------------------------------
// prep_proj: fat projection (8 nodes/block) + layer-0 alpha.
// ---------------------------------------------------------------------------
__global__ __launch_bounds__(256) void prep_proj_kernel(const float* __restrict__ x,
                                                        const float* __restrict__ w,
                                                        const float* __restrict__ b,
                                                        unsigned short* __restrict__ h_bf,
                                                        const float* __restrict__ q_s,
                                                        const float* __restrict__ q_d,
                                                        float4* __restrict__ als4,
                                                        float4* __restrict__ ald4) {
    int bx = blockIdx.x;
    int tid = threadIdx.x;
    __shared__ float xr[8][F_NODE];
    __shared__ float vbuf[8][128];
    __shared__ float qs_t[512];
    __shared__ float qd_t[512];
    qs_t[tid] = q_s[tid]; qs_t[256 + tid] = q_s[256 + tid];
    qd_t[tid] = q_d[tid]; qd_t[256 + tid] = q_d[256 + tid];
    if (tid < 8 * F_NODE) {
        int nl = tid / F_NODE, k = tid % F_NODE;
        xr[nl][k] = x[(size_t)(bx * 8 + nl) * F_NODE + k];
    }
    __syncthreads();
    int d = tid & 127;
    int halfsel = tid >> 7;
#pragma unroll
    for (int p = 0; p < 4; p++) {
        int nl = p * 2 + halfsel;
        float acc = b[d];
#pragma unroll
        for (int k = 0; k < F_NODE; k++) acc += xr[nl][k] * w[k * DIM + d];
        float v = fmaxf(acc, 0.f);
        h_bf[(size_t)(bx * 8 + nl) * DIM + d] = f2b(v);
        vbuf[nl][d] = v;
    }
    __syncthreads();
    int wave = tid >> 6, lane = tid & 63;
#pragma unroll
    for (int t = 0; t < 2; t++) {
        int nl = wave * 2 + t;
        int n = bx * 8 + nl;
        float2 v2 = *(const float2*)&vbuf[nl][2 * lane];
        int k4 = 2 * lane * 4;
        float ps[4], pd[4];
#pragma unroll
        for (int hh_ = 0; hh_ < 4; hh_++) {
            ps[hh_] = v2.x * qs_t[k4 + hh_] + v2.y * qs_t[k4 + 4 + hh_];
            pd[hh_] = v2.x * qd_t[k4 + hh_] + v2.y * qd_t[k4 + 4 + hh_];
        }
#pragma unroll
        for (int off = 32; off; off >>= 1) {
#pragma unroll
            for (int hh_ = 0; hh_ < 4; hh_++) {
                ps[hh_] += __shfl_xor(ps[hh_], off);
                pd[hh_] += __shfl_xor(pd[hh_], off);
            }
        }
        if (lane == 0) {
            als4[n] = make_float4(ps[0], ps[1], ps[2], ps[3]);
            ald4[n] = make_float4(pd[0], pd[1], pd[2], pd[3]);
        }
    }
}

// ---------------------------------------------------------------------------
// prep_scat: fixed-capacity CSR scatter, 4 edges/thread. NOT idempotent.
// ---------------------------------------------------------------------------
__global__ __launch_bounds__(256) void prep_scat_kernel(const int* __restrict__ edge_index,
                                                        int* __restrict__ degs,
                                                        int* __restrict__ csr_src) {
    int base = blockIdx.x * 1024;
    int tid = threadIdx.x;
#pragma unroll
    for (int k = 0; k < 4; k++) {
        int e = base + k * 256 + tid;
        if (e < E_TOTAL) {
            int s, d;
            if (e < N_EDGES) { s = edge_index[e]; d = edge_index[N_EDGES + e]; }
            else             { s = e - N_EDGES;   d = s; }
            int pos = atomicAdd(&degs[d], 1);
            if (pos < CSR_CAP) csr_src[d * CSR_CAP + pos] = s;
        }
    }
}

// ---------------------------------------------------------------------------
// agg3 (R7, verified R8: 21.6 -> 13.2 us/rep; VALUBusy 81%, Occ 67%, VGPR 32).
// Phase 1 (lane = edge): 4 exps from als4[src]+ald4[n], butterfly-reduce sum,
//   PRE-DIVIDE w' = w/sum, stash {w'4, byte-offset src*256} in LDS.
// Phase 2 (per edge): uniform ds_read offset + uniform ds_read_b128 w'4 +
//   1 v_add + 1 global load + 4 pk_fma. Epilogue: pack+store only.
// Remaining ceiling is the VALU issue rate (~8 inst/edge, 4 of them pk_fma).
// ---------------------------------------------------------------------------
template<int LYR, int REPS>
__global__ __launch_bounds__(256) void agg3_kernel(const unsigned short* __restrict__ h_bf,
                                                   const float4* __restrict__ als4,
                                                   const float4* __restrict__ ald4,
                                                   const int* __restrict__ degs,
                                                   const int* __restrict__ csr_src,
                                                   unsigned short* __restrict__ z) {
    __shared__ __align__(16) float wlds[4][CSR_CAP][4];
    __shared__ unsigned olds[4][CSR_CAP];
    int wave = threadIdx.x >> 6, lane = threadIdx.x & 63;
    int n = blockIdx.x * 4 + wave;
    if (n >= N_NODES) return;

    int deg = degs[n];
    deg = (deg < CSR_CAP) ? deg : CSR_CAP;
    const int* __restrict__ srcp = csr_src + (size_t)n * CSR_CAP;
    const unsigned char* __restrict__ hbase = (const unsigned char*)h_bf;
    float4 ad = ald4[n];
    unsigned lane4 = (unsigned)lane * 4u;

#pragma unroll 1
    for (int rep = 0; rep < REPS; ++rep) {
        // ---- phase 1: lane = edge ----
        float4 w4 = make_float4(0.f, 0.f, 0.f, 0.f);
        unsigned off_ = 0;
        if (lane < deg) {
            int s = srcp[lane];                       // coalesced
            off_ = (unsigned)s * 256u;                // byte offset into h_bf row
            float4 as = als4[s];                      // 16B gather, one per edge
            float v;
            v = as.x + ad.x; v = fmaxf(v, NEG_SLOPE * v); w4.x = __expf(fminf(v, 60.f));
            v = as.y + ad.y; v = fmaxf(v, NEG_SLOPE * v); w4.y = __expf(fminf(v, 60.f));
            v = as.z + ad.z; v = fmaxf(v, NEG_SLOPE * v); w4.z = __expf(fminf(v, 60.f));
            v = as.w + ad.w; v = fmaxf(v, NEG_SLOPE * v); w4.w = __expf(fminf(v, 60.f));
        }
        float lsx = w4.x, lsy = w4.y, lsz = w4.z, lsw = w4.w;
#pragma unroll
        for (int o = 32; o; o >>= 1) {
            lsx += __shfl_xor(lsx, o);
            lsy += __shfl_xor(lsy, o);
            lsz += __shfl_xor(lsz, o);
            lsw += __shfl_xor(lsw, o);
        }
        float ix = 1.f / lsx, iy = 1.f / lsy, iz = 1.f / lsz, iw = 1.f / lsw;
        if (lane < deg) {
            wlds[wave][lane][0] = w4.x * ix;
            wlds[wave][lane][1] = w4.y * iy;
            wlds[wave][lane][2] = w4.z * iz;
            wlds[wave][lane][3] = w4.w * iw;
            olds[wave][lane] = off_;
        }
        // ---- phase 2: gather-FMA ----
        f32x2 acc2[4] = {};
        int e = 0;
        for (; e + 4 <= deg; e += 4) {
            unsigned o0 = olds[wave][e];
            unsigned o1 = olds[wave][e + 1];
            unsigned o2 = olds[wave][e + 2];
            unsigned o3 = olds[wave][e + 3];
            unsigned hv0 = *(const unsigned*)(hbase + o0 + lane4);
            unsigned hv1 = *(const unsigned*)(hbase + o1 + lane4);
            unsigned hv2 = *(const unsigned*)(hbase + o2 + lane4);
            unsigned hv3 = *(const unsigned*)(hbase + o3 + lane4);
            float4 w0 = *(const float4*)&wlds[wave][e][0];
            float4 w1 = *(const float4*)&wlds[wave][e + 1][0];
            float4 w2 = *(const float4*)&wlds[wave][e + 2][0];
            float4 w3 = *(const float4*)&wlds[wave][e + 3][0];
            f32x2 f;
            f.x = blo(hv0); f.y = bhi(hv0);
            acc2[0] += w0.x * f; acc2[1] += w0.y * f; acc2[2] += w0.z * f; acc2[3] += w0.w * f;
            f.x = blo(hv1); f.y = bhi(hv1);
            acc2[0] += w1.x * f; acc2[1] += w1.y * f; acc2[2] += w1.z * f; acc2[3] += w1.w * f;
            f.x = blo(hv2); f.y = bhi(hv2);
            acc2[0] += w2.x * f; acc2[1] += w2.y * f; acc2[2] += w2.z * f; acc2[3] += w2.w * f;
            f.x = blo(hv3); f.y = bhi(hv3);
            acc2[0] += w3.x * f; acc2[1] += w3.y * f; acc2[2] += w3.z * f; acc2[3] += w3.w * f;
        }
        for (; e < deg; e++) {
            unsigned o0 = olds[wave][e];
            unsigned hv0 = *(const unsigned*)(hbase + o0 + lane4);
            float4 w0 = *(const float4*)&wlds[wave][e][0];
            f32x2 f;
            f.x = blo(hv0); f.y = bhi(hv0);
            acc2[0] += w0.x * f; acc2[1] += w0.y * f; acc2[2] += w0.z * f; acc2[3] += w0.w * f;
        }
        // ---- epilogue: pack & store (already normalized) ----
        uint4 pb;
        unsigned int* pc = &pb.x;
#pragma unroll
        for (int hh_ = 0; hh_ < 4; hh_++) {
            pc[hh_] = (unsigned)f2b(acc2[hh_].x) | ((unsigned)f2b(acc2[hh_].y) << 16);
        }
        *(uint4*)(z + (size_t)n * 512 + lane * 8) = pb;
    }
}

// ---------------------------------------------------------------------------
// zgemm v2 (REVERTED R10): out = z[M,512] @ wt2[128,512]^T, fused bias + LN
// + ReLU + bf16 residual + next-layer alpha. BM=64, 512 thr / 8 waves;
// wave=(msub,nh) computes 16 rows x 64 cols. Verified R5: 14.0 us/rep.
// R9 post-mortem: BM=32 regressed (~+12 us/launch) — per-block B-staging
// (full 128x512 weight, 131 KB) is constant w.r.t. BM, so halving BM doubled
// total staging work while the block is staging-dominated (MfmaUtil 7%).
// BM=64 is the verified sweet spot for this structure.
// ---------------------------------------------------------------------------
template<int LYR>
__global__ __launch_bounds__(512) void zgemm_kernel(const unsigned short* __restrict__ z,
                                                    const unsigned short* __restrict__ wt2_l,
                                                    const float* __restrict__ b_gat,
                                                    const float* __restrict__ ln_w,
                                                    const float* __restrict__ ln_b,
                                                    const unsigned short* __restrict__ hb_in,
                                                    unsigned short* __restrict__ hb_out,
                                                    const float* __restrict__ q_s_next,
                                                    const float* __restrict__ q_d_next,
                                                    float4* __restrict__ als4,
                                                    float4* __restrict__ ald4,
                                                    int M) {
    __shared__ __align__(16) unsigned short As[64 * 136];
    __shared__ __align__(16) unsigned short Bs[128 * 136];
    __shared__ float redS[2][4][16];
    __shared__ float redQ[2][4][16];
    __shared__ float redPS[2][4][16][4];
    __shared__ float redPD[2][4][16][4];
    int tid = threadIdx.x;
    int m0 = blockIdx.x << 6;
    int wave = tid >> 6, lane = tid & 63;
    int lr = lane & 15, lg = lane >> 4;
    int msub = wave & 3, nh = wave >> 2;

    const uint4 zero4 = make_uint4(0, 0, 0, 0);
    f32x4 acc[4] = {};
    for (int kc = 0; kc < 4; kc++) {
#pragma unroll
        for (int p = 0; p < 2; p++) {        // A: 64 rows x 16 kg (512 thr)
            int i = p * 512 + tid;
            int row = i >> 4, kg = i & 15;
            int arow = m0 + row;
            uint4 av = (arow < M) ? *(const uint4*)(z + (size_t)arow * 512 + kc * 128 + kg * 8) : zero4;
            *(uint4*)&As[row * 136 + kg * 8] = av;
        }
#pragma unroll
        for (int p = 0; p < 4; p++) {        // B: 128 rows x 16 kg (512 thr)
            int i = p * 512 + tid;
            int row = i >> 4, kg = i & 15;
            uint4 bv = *(const uint4*)(wt2_l + (size_t)row * 512 + kc * 128 + kg * 8);
            *(uint4*)&Bs[row * 136 + kg * 8] = bv;
        }
        __syncthreads();
#pragma unroll
        for (int ks = 0; ks < 4; ks++) {
            bf16x8 af = *(const bf16x8*)&As[(msub * 16 + lr) * 136 + ks * 32 + lg * 8];
#pragma unroll
            for (int nt2 = 0; nt2 < 4; nt2++) {
                int nt = nh * 4 + nt2;
                bf16x8 bf_ = *(const bf16x8*)&Bs[(nt * 16 + lr) * 136 + ks * 32 + lg * 8];
                acc[nt2] = __builtin_amdgcn_mfma_f32_16x16x32_bf16(af, bf_, acc[nt2], 0, 0, 0);
            }
        }
        __syncthreads();
    }

    // ---- epilogue: bias + LN (cross-half LDS reduce) + relu + residual ----
    float bg[4], lnw[4], lnb[4];
#pragma unroll
    for (int nt2 = 0; nt2 < 4; nt2++) {
        int col = nh * 64 + nt2 * 16 + lr;
        bg[nt2] = b_gat[col]; lnw[nt2] = ln_w[col]; lnb[nt2] = ln_b[col];
    }
    const bool do_alpha = (LYR + 1 < NLAYER);
    float4 qs4[4], qd4[4];
    if (do_alpha) {
#pragma unroll
        for (int nt2 = 0; nt2 < 4; nt2++) {
            int col = nh * 64 + nt2 * 16 + lr;
            qs4[nt2] = *(const float4*)(q_s_next + (size_t)col * 4);
            qd4[nt2] = *(const float4*)(q_d_next + (size_t)col * 4);
        }
    }
    float g[4][4];                       // [nt2][r]
#pragma unroll
    for (int nt2 = 0; nt2 < 4; nt2++)
#pragma unroll
        for (int r = 0; r < 4; r++) g[nt2][r] = acc[nt2][r] + bg[nt2];
#pragma unroll
    for (int r = 0; r < 4; r++) {
        float s = 0.f, q = 0.f;
#pragma unroll
        for (int nt2 = 0; nt2 < 4; nt2++) { s += g[nt2][r]; q += g[nt2][r] * g[nt2][r]; }
#pragma unroll
        for (int off = 1; off < 16; off <<= 1) { s += __shfl_xor(s, off); q += __shfl_xor(q, off); }
        if (lr == 0) { redS[nh][msub][lg * 4 + r] = s; redQ[nh][msub][lg * 4 + r] = q; }
    }
    __syncthreads();
    float o[4][4];
#pragma unroll
    for (int r = 0; r < 4; r++) {
        int row = m0 + msub * 16 + lg * 4 + r;
        bool valid = (row < M);
        int ri = lg * 4 + r;
        float mu = (redS[0][msub][ri] + redS[1][msub][ri]) * (1.f / 128.f);
        float qq = (redQ[0][msub][ri] + redQ[1][msub][ri]) * (1.f / 128.f);
        float rstd = rsqrtf(fmaxf(qq - mu * mu, 0.f) + LN_EPS);
#pragma unroll
        for (int nt2 = 0; nt2 < 4; nt2++) {
            int col = nh * 64 + nt2 * 16 + lr;
            float hv = valid ? b2f(hb_in[(size_t)row * 128 + col]) : 0.f;
            o[nt2][r] = fmaxf((g[nt2][r] - mu) * rstd * lnw[nt2] + lnb[nt2], 0.f) + hv;
            if (valid) hb_out[(size_t)row * 128 + col] = f2b(o[nt2][r]);
        }
    }
    if (do_alpha) {
        float ps[4][4] = {}, pd[4][4] = {};   // [r][h]
#pragma unroll
        for (int r = 0; r < 4; r++)
#pragma unroll
            for (int nt2 = 0; nt2 < 4; nt2++) {
                ps[r][0] += o[nt2][r] * qs4[nt2].x; pd[r][0] += o[nt2][r] * qd4[nt2].x;
                ps[r][1] += o[nt2][r] * qs4[nt2].y; pd[r][1] += o[nt2][r] * qd4[nt2].y;
                ps[r][2] += o[nt2][r] * qs4[nt2].z; pd[r][2] += o[nt2][r] * qd4[nt2].z;
                ps[r][3] += o[nt2][r] * qs4[nt2].w; pd[r][3] += o[nt2][r] * qd4[nt2].w;
            }
#pragma unroll
        for (int r = 0; r < 4; r++)
#pragma unroll
            for (int off = 1; off < 16; off <<= 1)
#pragma unroll
                for (int hh_ = 0; hh_ < 4; hh_++) {
                    ps[r][hh_] += __shfl_xor(ps[r][hh_], off);
                    pd[r][hh_] += __shfl_xor(pd[r][hh_], off);
                }
        if (lr == 0) {
#pragma unroll
            for (int r = 0; r < 4; r++)
#pragma unroll
                for (int hh_ = 0; hh_ < 4; hh_++) {
                    redPS[nh][msub][lg * 4 + r][hh_] = ps[r][hh_];
                    redPD[nh][msub][lg * 4 + r][hh_] = pd[r][hh_];
                }
        }
        __syncthreads();
        if (nh == 0 && lr == 0) {
#pragma unroll
            for (int r = 0; r < 4; r++) {
                int row = m0 + msub * 16 + lg * 4 + r;
                int ri = lg * 4 + r;
                if (row < M) {
                    als4[row] = make_float4(redPS[0][msub][ri][0] + redPS[1][msub][ri][0],
                                            redPS[0][msub][ri][1] + redPS[1][msub][ri][1],
                                            redPS[0][msub][ri][2] + redPS[1][msub][ri][2],
                                            redPS[0][msub][ri][3] + redPS[1][msub][ri][3]);
                    ald4[row] = make_float4(redPD[0][msub][ri][0] + redPD[1][msub][ri][0],
                                            redPD[0][msub][ri][1] + redPD[1][msub][ri][1],
                                            redPD[0][msub][ri][2] + redPD[1][msub][ri][2],
                                            redPD[0][msub][ri][3] + redPD[1][msub][ri][3]);
                }
            }
        }
    }
}

// ---------------------------------------------------------------------------
// pool4: per-graph pooling split 4 ways — block (g,q4) computes partial
// sum/max over its quarter of graph g's nodes.
// ---------------------------------------------------------------------------
__device__ int lower_bound_dev(const int* a, int n, int v) {
    int lo = 0, hi = n;
    while (lo < hi) { int mid = (lo + hi) >> 1; if (a[mid] < v) lo = mid + 1; else hi = mid; }
    return lo;
}

__global__ __launch_bounds__(256) void pool4_kernel(const unsigned short* __restrict__ h,
                                                    const int* __restrict__ batch,
                                                    float* __restrict__ pool_ws) {
    int g = blockIdx.x >> 2, q4 = blockIdx.x & 3;
    int tid = threadIdx.x;
    __shared__ int bounds[2];
    __shared__ float psum[2][128];
    __shared__ float pmax[2][128];
    if (tid < 2) bounds[tid] = lower_bound_dev(batch, N_NODES, g + tid);
    __syncthreads();
    int lo = bounds[0], hi = bounds[1];
    int cnt = hi - lo;
    int per = (cnt + 3) >> 2;
    int beg = lo + q4 * per;
    int end = min(beg + per, hi);
    int rq = tid >> 7, d = tid & 127;
    float s = 0.f, m = -1e30f;
    for (int i = beg + rq; i < end; i += 2) {
        float v = b2f(h[(size_t)i * DIM + d]);
        s += v; m = fmaxf(m, v);
    }
    psum[rq][d] = s; pmax[rq][d] = m;
    __syncthreads();
    if (tid < 128) {
        float S = psum[0][d] + psum[1][d];
        float M = fmaxf(pmax[0][d], pmax[1][d]);
        pool_ws[(((size_t)g * 4 + q4) * 2 + 0) * 128 + d] = S;
        pool_ws[(((size_t)g * 4 + q4) * 2 + 1) * 128 + d] = M;
    }
}

// ---------------------------------------------------------------------------
// tail: per-graph MLP tail; pooling phase reads the 4 partials from pool_ws.
// ---------------------------------------------------------------------------
__global__ __launch_bounds__(512) void tail_kernel(
    const float* __restrict__ pool_ws, const int* __restrict__ batch,
    const float* __restrict__ tda,
    const float* __restrict__ w_t1, const float* __restrict__ b_t1,
    const float* __restrict__ w_t2, const float* __restrict__ b_t2,
    const float* __restrict__ w_sh1, const float* __restrict__ b_sh1,
    const float* __restrict__ w_sh2, const float* __restrict__ b_sh2,
    const float* __restrict__ w_h1, const float* __restrict__ b_h1,
    const float* __restrict__ w_h2, const float* __restrict__ b_h2,
    float* __restrict__ out) {
    __shared__ int bounds[2];
    __shared__ float comb[320];
    __shared__ float tr[F_TDA];
    __shared__ float t1[64];
    __shared__ float s1o[256];
    __shared__ float s2o[128];
    __shared__ float prods[NTASK * 64];
    int g = blockIdx.x, tid = threadIdx.x;

    if (tid < 2) bounds[tid] = lower_bound_dev(batch, N_NODES, g + tid);
    if (tid >= 2 && tid - 2 < F_TDA) tr[tid - 2] = tda[g * F_TDA + (tid - 2)];
    __syncthreads();
    int cnt = bounds[1] - bounds[0];
    if (tid < 128) {
        float S = 0.f, M = -1e30f;
#pragma unroll
        for (int q4 = 0; q4 < 4; q4++) {
            S += pool_ws[(((size_t)g * 4 + q4) * 2 + 0) * 128 + tid];
            M = fmaxf(M, pool_ws[(((size_t)g * 4 + q4) * 2 + 1) * 128 + tid]);
        }
        comb[tid] = S / fmaxf((float)cnt, 1.f);
        comb[128 + tid] = (cnt > 0) ? M : 0.f;
    } else if (tid >= 128 && tid < 192) {
        int j = tid - 128;
        float a = b_t1[j];
#pragma unroll
        for (int k = 0; k < F_TDA; k++) a += tr[k] * w_t1[k * 64 + j];
        t1[j] = fmaxf(a, 0.f);
    }
    __syncthreads();
    if (tid < 64) {
        float a = b_t2[tid];
#pragma unroll
        for (int k = 0; k < 64; k++) a += t1[k] * w_t2[k * 64 + tid];
        comb[256 + tid] = fmaxf(a, 0.f);
    }
    __syncthreads();
    if (tid < 256) {
        float a = b_sh1[tid];
        for (int k = 0; k < 320; k++) a += comb[k] * w_sh1[k * 256 + tid];
        s1o[tid] = fmaxf(a, 0.f);
    }
    __syncthreads();
    if (tid < 128) {
        float a = b_sh2[tid];
        for (int k = 0; k < 256; k++) a += s1o[k] * w_sh2[k * 128 + tid];
        s2o[tid] = fmaxf(a, 0.f);
    }
    __syncthreads();
    if (tid < NTASK * 64) {
        int t = tid >> 6, k = tid & 63;
        float a = b_h1[t * 64 + k];
#pragma unroll 16
        for (int dd = 0; dd < 128; dd++) a += s2o[dd] * w_h1[(size_t)t * 8192 + dd * 64 + k];
        prods[tid] = fmaxf(a, 0.f) * w_h2[t * 64 + k];
    }
    __syncthreads();
    if (tid < NTASK) {
        float p = b_h2[tid];
#pragma unroll 16
        for (int k = 0; k < 64; k++) p += prods[tid * 64 + k];
        out[tid * 256 + g] = p;
    }
}

// ---------------------------------------------------------------------------
extern "C" void kernel_launch(void* const* d_in, const int* in_sizes, int n_in,
                              void* d_out, int out_size, void* d_ws, size_t ws_size,
                              hipStream_t stream) {
    const float* x        = (const float*)d_in[0];
    const int*   edge_idx = (const int*)  d_in[1];
    const int*   batch    = (const int*)  d_in[2];
    const float* tda      = (const float*)d_in[3];
    const float* w_in     = (const float*)d_in[4];
    const float* b_in     = (const float*)d_in[5];
    const float* w_gat    = (const float*)d_in[6];
    const float* a_src    = (const float*)d_in[7];
    const float* a_dst    = (const float*)d_in[8];
    const float* b_gat    = (const float*)d_in[9];
    const float* ln_w     = (const float*)d_in[10];
    const float* ln_b     = (const float*)d_in[11];
    const float* w_tda1   = (const float*)d_in[12];
    const float* b_tda1   = (const float*)d_in[13];
    const float* w_tda2   = (const float*)d_in[14];
    const float* b_tda2   = (const float*)d_in[15];
    const float* w_sh1    = (const float*)d_in[16];
    const float* b_sh1    = (const float*)d_in[17];
    const float* w_sh2    = (const float*)d_in[18];
    const float* b_sh2    = (const float*)d_in[19];
    const float* w_h1     = (const float*)d_in[20];
    const float* b_h1     = (const float*)d_in[21];
    const float* w_h2     = (const float*)d_in[22];
    const float* b_h2     = (const float*)d_in[23];
    float* out = (float*)d_out;

    size_t off = 0;
    auto alloc = [&](size_t bytes) -> void* {
        void* p = (char*)d_ws + off;
        off += (bytes + 255) & ~(size_t)255;
        return p;
    };
    unsigned short* hb_a   = (unsigned short*)alloc((size_t)N_NODES * DIM * 2);
    unsigned short* hb_b   = (unsigned short*)alloc((size_t)N_NODES * DIM * 2);
    unsigned short* z      = (unsigned short*)alloc((size_t)N_NODES * 512 * 2);
    unsigned short* wt2    = (unsigned short*)alloc((size_t)NLAYER * 128 * 512 * 2);
    float*          q_s    = (float*)alloc((size_t)NLAYER * 128 * 4 * 4);
    float*          q_d    = (float*)alloc((size_t)NLAYER * 128 * 4 * 4);
    float4*         als4   = (float4*)alloc((size_t)N_NODES * 16);
    float4*         ald4   = (float4*)alloc((size_t)N_NODES * 16);
    int*            degs   = (int*)  alloc((size_t)N_NODES * 4);
    int*            csrsrc = (int*)  alloc((size_t)N_NODES * CSR_CAP * 4);
    float*          poolws = (float*)alloc((size_t)N_GRAPHS * 4 * 2 * 128 * 4);

    // qprep also zeroes degs (blocks 1152..1171) — no separate memset
    qprep_kernel<<<1172, 256, 0, stream>>>(w_gat, a_src, a_dst, wt2, q_s, q_d, degs);

    prep_proj_kernel<<<2500, 256, 0, stream>>>(x, w_in, b_in, hb_a, q_s, q_d, als4, ald4);
    int sb = (E_TOTAL + 1023) / 1024;   // 333
    prep_scat_kernel<<<sb, 256, 0, stream>>>(edge_idx, degs, csrsrc);

    int ab = (N_NODES + 3) / 4;
    int gb = (N_NODES + 63) / 64;        // 313 blocks (BM=64, verified v2)
    // layer 0: hb_a -> hb_b
    agg3_kernel<0, 1><<<ab, 256, 0, stream>>>(hb_a, als4, ald4, degs, csrsrc, z);
    zgemm_kernel<0><<<gb, 512, 0, stream>>>(z, wt2,
        b_gat, ln_w, ln_b, hb_a, hb_b, q_s + 512, q_d + 512, als4, ald4, N_NODES);
    // layer 1: hb_b -> hb_a
    agg3_kernel<1, 1><<<ab, 256, 0, stream>>>(hb_b, als4, ald4, degs, csrsrc, z);
    zgemm_kernel<1><<<gb, 512, 0, stream>>>(z, wt2 + 65536,
        b_gat + DIM, ln_w + DIM, ln_b + DIM, hb_b, hb_a, q_s + 1024, q_d + 1024,
        als4, ald4, N_NODES);
    // layer 2: hb_a -> hb_b
    agg3_kernel<2, 1><<<ab, 256, 0, stream>>>(hb_a, als4, ald4, degs, csrsrc, z);
    zgemm_kernel<2><<<gb, 512, 0, stream>>>(z, wt2 + 131072,
        b_gat + 2 * DIM, ln_w + 2 * DIM, ln_b + 2 * DIM, hb_a, hb_b,
        nullptr, nullptr, als4, ald4, N_NODES);

    pool4_kernel<<<N_GRAPHS * 4, 256, 0, stream>>>(hb_b, batch, poolws);
    tail_kernel<<<N_GRAPHS, 512, 0, stream>>>(
        poolws, batch, tda, w_tda1, b_tda1, w_tda2, b_tda2,
        w_sh1, b_sh1, w_sh2, b_sh2, w_h1, b_h1, w_h2, b_h2, out);
}